// Round 1
// baseline (871.985 us; speedup 1.0000x reference)
//
#include <hip/hip_runtime.h>
#include <hip/hip_bf16.h>

#define BN_EPS 1e-5f
#define NBLK_STAT 128

// ---------------- degree / CSR build ----------------

__global__ void k_degree(const int* __restrict__ dst, int* __restrict__ cnt, int E) {
    int e = blockIdx.x * blockDim.x + threadIdx.x;
    if (e < E) atomicAdd(&cnt[dst[e]], 1);
}

__global__ __launch_bounds__(1024) void k_scan(const int* __restrict__ cnt,
                                               int* __restrict__ rowptr,
                                               int* __restrict__ pos,
                                               float* __restrict__ dinv, int n) {
    __shared__ int lds[1024];
    int tid = threadIdx.x;
    int chunk = (n + 1023) >> 10;
    int start = tid * chunk;
    int end = min(start + chunk, n);
    int s = 0;
    for (int i = start; i < end; ++i) s += cnt[i];
    lds[tid] = s;
    __syncthreads();
    for (int off = 1; off < 1024; off <<= 1) {
        int v = lds[tid];
        int add = (tid >= off) ? lds[tid - off] : 0;
        __syncthreads();
        lds[tid] = v + add;
        __syncthreads();
    }
    int run = (tid == 0) ? 0 : lds[tid - 1];
    for (int i = start; i < end; ++i) {
        rowptr[i] = run;
        pos[i] = run;
        int c = cnt[i];
        run += c;
        dinv[i] = rsqrtf((float)c + 1.0f);
    }
    if (tid == 1023) rowptr[n] = run;
}

__global__ void k_fill(const int* __restrict__ src, const int* __restrict__ dst,
                       int* __restrict__ pos, int* __restrict__ col, int E) {
    int e = blockIdx.x * blockDim.x + threadIdx.x;
    if (e < E) {
        int d = dst[e];
        int p = atomicAdd(&pos[d], 1);
        col[p] = src[e];
    }
}

// ---------------- GEMM: C[n,OUT] = transform(A[n,K]) @ W[K,OUT], epilogue *dinv[row] ----------------
// transform (if scale != null): a = relu(a*scale[k] + shift[k])   (fused BN+ReLU of previous layer)

__global__ __launch_bounds__(256) void k_gemm(const float* __restrict__ A,
                                              const float* __restrict__ W,
                                              float* __restrict__ C,
                                              const float* __restrict__ scale,
                                              const float* __restrict__ shift,
                                              const float* __restrict__ dinv,
                                              int n, int K, int OUT) {
    __shared__ float As[64][68];
    __shared__ float Ws[64][68];
    int row0 = blockIdx.x * 64;
    int col0 = blockIdx.y * 64;
    int tid = threadIdx.x;
    int tc = tid & 15;
    int tr = tid >> 4;
    float acc[4][4] = {{0.f}};

    for (int k0 = 0; k0 < K; k0 += 64) {
        for (int i = tid; i < 1024; i += 256) {
            int r = i >> 4;
            int c4 = (i & 15) << 2;
            int gr = row0 + r;
            float4 v = make_float4(0.f, 0.f, 0.f, 0.f);
            if (gr < n) v = *(const float4*)(A + (size_t)gr * K + (k0 + c4));
            if (scale) {
                const float4 sc = *(const float4*)(scale + k0 + c4);
                const float4 sh = *(const float4*)(shift + k0 + c4);
                v.x = fmaxf(v.x * sc.x + sh.x, 0.f);
                v.y = fmaxf(v.y * sc.y + sh.y, 0.f);
                v.z = fmaxf(v.z * sc.z + sh.z, 0.f);
                v.w = fmaxf(v.w * sc.w + sh.w, 0.f);
            }
            *(float4*)&As[r][c4] = v;
            float4 wv = *(const float4*)(W + (size_t)(k0 + r) * OUT + (col0 + c4));
            *(float4*)&Ws[r][c4] = wv;
        }
        __syncthreads();
        #pragma unroll
        for (int kk = 0; kk < 64; kk += 4) {
            float4 w0 = *(const float4*)&Ws[kk + 0][tc << 2];
            float4 w1 = *(const float4*)&Ws[kk + 1][tc << 2];
            float4 w2 = *(const float4*)&Ws[kk + 2][tc << 2];
            float4 w3 = *(const float4*)&Ws[kk + 3][tc << 2];
            #pragma unroll
            for (int i = 0; i < 4; ++i) {
                float4 a = *(const float4*)&As[(tr << 2) + i][kk];
                acc[i][0] += a.x * w0.x + a.y * w1.x + a.z * w2.x + a.w * w3.x;
                acc[i][1] += a.x * w0.y + a.y * w1.y + a.z * w2.y + a.w * w3.y;
                acc[i][2] += a.x * w0.z + a.y * w1.z + a.z * w2.z + a.w * w3.z;
                acc[i][3] += a.x * w0.w + a.y * w1.w + a.z * w2.w + a.w * w3.w;
            }
        }
        __syncthreads();
    }
    #pragma unroll
    for (int i = 0; i < 4; ++i) {
        int gr = row0 + (tr << 2) + i;
        if (gr >= n) continue;
        float dv = dinv[gr];
        float4 o = make_float4(acc[i][0] * dv, acc[i][1] * dv, acc[i][2] * dv, acc[i][3] * dv);
        *(float4*)(C + (size_t)gr * OUT + col0 + (tc << 2)) = o;
    }
}

// ---------------- aggregation: out[i] = dinv[i] * (Hs[i] + sum_{src in N(i)} Hs[src]) ----------------
// width 64: one wave per node, lane = channel
__global__ void k_agg64(const float* __restrict__ Hs, const float* __restrict__ dinv,
                        const int* __restrict__ rowptr, const int* __restrict__ col,
                        float* __restrict__ out, int n) {
    int node = (blockIdx.x * blockDim.x + threadIdx.x) >> 6;
    int lane = threadIdx.x & 63;
    if (node >= n) return;
    float s0 = Hs[(size_t)node * 64 + lane];
    float s1 = 0.f, s2 = 0.f, s3 = 0.f;
    int b = rowptr[node], e = rowptr[node + 1];
    int j = b;
    for (; j + 4 <= e; j += 4) {
        int i0 = col[j], i1 = col[j + 1], i2 = col[j + 2], i3 = col[j + 3];
        s0 += Hs[(size_t)i0 * 64 + lane];
        s1 += Hs[(size_t)i1 * 64 + lane];
        s2 += Hs[(size_t)i2 * 64 + lane];
        s3 += Hs[(size_t)i3 * 64 + lane];
    }
    for (; j < e; ++j) s0 += Hs[(size_t)col[j] * 64 + lane];
    out[(size_t)node * 64 + lane] = dinv[node] * ((s0 + s1) + (s2 + s3));
}

// width 256: one wave per node, lane = float4-group of channels
__global__ void k_agg256(const float4* __restrict__ Hs, const float* __restrict__ dinv,
                         const int* __restrict__ rowptr, const int* __restrict__ col,
                         float4* __restrict__ out, int n) {
    int node = (blockIdx.x * blockDim.x + threadIdx.x) >> 6;
    int lane = threadIdx.x & 63;
    if (node >= n) return;
    float4 a = Hs[(size_t)node * 64 + lane];
    float s0 = a.x, s1 = a.y, s2 = a.z, s3 = a.w;
    int b = rowptr[node], e = rowptr[node + 1];
    for (int j = b; j < e; ++j) {
        float4 v = Hs[(size_t)col[j] * 64 + lane];
        s0 += v.x; s1 += v.y; s2 += v.z; s3 += v.w;
    }
    float dv = dinv[node];
    out[(size_t)node * 64 + lane] = make_float4(s0 * dv, s1 * dv, s2 * dv, s3 * dv);
}

// ---------------- BN statistics ----------------
// part[b*W+c] = partial sum, part[(nblk+b)*W+c] = partial sumsq

__global__ __launch_bounds__(256) void k_bnstat1(const float* __restrict__ X,
                                                 float* __restrict__ part, int n, int W) {
    int lanes = 256 / W;
    int c = threadIdx.x & (W - 1);
    int rsub = threadIdx.x / W;
    int rows_per_blk = (n + gridDim.x - 1) / gridDim.x;
    int r0 = blockIdx.x * rows_per_blk;
    int r1 = min(r0 + rows_per_blk, n);
    float s = 0.f, s2 = 0.f;
    for (int r = r0 + rsub; r < r1; r += lanes) {
        float v = X[(size_t)r * W + c];
        s += v;
        s2 += v * v;
    }
    __shared__ float ls[256], ls2[256];
    ls[threadIdx.x] = s;
    ls2[threadIdx.x] = s2;
    __syncthreads();
    if (rsub == 0) {
        for (int k = 1; k < lanes; ++k) {
            s += ls[k * W + c];
            s2 += ls2[k * W + c];
        }
        part[(size_t)blockIdx.x * W + c] = s;
        part[(size_t)(gridDim.x + blockIdx.x) * W + c] = s2;
    }
}

__global__ void k_bnstat2(const float* __restrict__ part, const float* __restrict__ g,
                          const float* __restrict__ be, float* __restrict__ scale,
                          float* __restrict__ shift, int nblk, int W, float inv_n) {
    int c = blockIdx.x * blockDim.x + threadIdx.x;
    if (c >= W) return;
    float s = 0.f, s2 = 0.f;
    for (int b = 0; b < nblk; ++b) {
        s += part[(size_t)b * W + c];
        s2 += part[(size_t)(nblk + b) * W + c];
    }
    float m = s * inv_n;
    float v = s2 * inv_n - m * m;
    float sc = g[c] * rsqrtf(v + BN_EPS);
    scale[c] = sc;
    shift[c] = be[c] - m * sc;
}

// ---------------- final: out = relu(out*scale[c] + shift[c] + x) (in place, W=256) ----------------

__global__ void k_final(float* __restrict__ out, const float* __restrict__ x,
                        const float* __restrict__ scale, const float* __restrict__ shift, int n) {
    int idx = blockIdx.x * blockDim.x + threadIdx.x;
    int total = n * 64;  // float4 count
    for (int i = idx; i < total; i += gridDim.x * blockDim.x) {
        float4 v = *(const float4*)(out + (size_t)i * 4);
        float4 xv = *(const float4*)(x + (size_t)i * 4);
        int c4 = (i & 63) << 2;
        float4 sc = *(const float4*)(scale + c4);
        float4 sh = *(const float4*)(shift + c4);
        v.x = fmaxf(v.x * sc.x + sh.x + xv.x, 0.f);
        v.y = fmaxf(v.y * sc.y + sh.y + xv.y, 0.f);
        v.z = fmaxf(v.z * sc.z + sh.z + xv.z, 0.f);
        v.w = fmaxf(v.w * sc.w + sh.w + xv.w, 0.f);
        *(float4*)(out + (size_t)i * 4) = v;
    }
}

// ---------------- launch ----------------

extern "C" void kernel_launch(void* const* d_in, const int* in_sizes, int n_in,
                              void* d_out, int out_size, void* d_ws, size_t ws_size,
                              hipStream_t stream) {
    const float* x   = (const float*)d_in[0];
    const int*   ei  = (const int*)d_in[1];
    const int    N   = in_sizes[2];       // batch has N elements
    const int    E   = in_sizes[1] / 2;
    const float* W1  = (const float*)d_in[3];
    const float* g1  = (const float*)d_in[5];
    const float* be1 = (const float*)d_in[6];
    const float* W2  = (const float*)d_in[7];
    const float* g2  = (const float*)d_in[9];
    const float* be2 = (const float*)d_in[10];
    const float* W3  = (const float*)d_in[11];
    const float* g3  = (const float*)d_in[13];
    const float* be3 = (const float*)d_in[14];
    float* out = (float*)d_out;

    char* p = (char*)d_ws;
    auto alloc = [&](size_t bytes) {
        char* q = p;
        p += (bytes + 255) & ~(size_t)255;
        return q;
    };
    int*   cnt    = (int*)alloc((size_t)N * 4);
    int*   rowptr = (int*)alloc((size_t)(N + 1) * 4);
    int*   pos    = (int*)alloc((size_t)N * 4);
    int*   colv   = (int*)alloc((size_t)E * 4);
    float* dinv   = (float*)alloc((size_t)N * 4);
    float* bufA   = (float*)alloc((size_t)N * 64 * 4);   // Hs (row-scaled h)
    float* bufB   = (float*)alloc((size_t)N * 64 * 4);   // agg
    float* bufC   = (float*)alloc((size_t)N * 256 * 4);  // Hs3
    float* part   = (float*)alloc((size_t)2 * NBLK_STAT * 256 * 4);
    float* scale  = (float*)alloc(256 * 4);
    float* shift  = (float*)alloc(256 * 4);

    const int* srcp = ei;
    const int* dstp = ei + E;

    hipMemsetAsync(cnt, 0, (size_t)N * 4, stream);
    int eb = (E + 255) / 256;
    k_degree<<<eb, 256, 0, stream>>>(dstp, cnt, E);
    k_scan<<<1, 1024, 0, stream>>>(cnt, rowptr, pos, dinv, N);
    k_fill<<<eb, 256, 0, stream>>>(srcp, dstp, pos, colv, E);

    dim3 gemm_g((N + 63) / 64, 1);
    dim3 gemm3_g((N + 63) / 64, 4);
    int aggb = (N * 64 + 255) / 256;  // one wave per node

    // conv1: x -> h1
    k_gemm<<<gemm_g, 256, 0, stream>>>(x, W1, bufA, nullptr, nullptr, dinv, N, 256, 64);
    k_agg64<<<aggb, 256, 0, stream>>>(bufA, dinv, rowptr, colv, bufB, N);
    k_bnstat1<<<NBLK_STAT, 256, 0, stream>>>(bufB, part, N, 64);
    k_bnstat2<<<1, 64, 0, stream>>>(part, g1, be1, scale, shift, NBLK_STAT, 64, 1.0f / N);

    // conv2: bn+relu fused into GEMM A-load
    k_gemm<<<gemm_g, 256, 0, stream>>>(bufB, W2, bufA, scale, shift, dinv, N, 64, 64);
    k_agg64<<<aggb, 256, 0, stream>>>(bufA, dinv, rowptr, colv, bufB, N);
    k_bnstat1<<<NBLK_STAT, 256, 0, stream>>>(bufB, part, N, 64);
    k_bnstat2<<<1, 64, 0, stream>>>(part, g2, be2, scale, shift, NBLK_STAT, 64, 1.0f / N);

    // conv3: 64 -> 256
    k_gemm<<<gemm3_g, 256, 0, stream>>>(bufB, W3, bufC, scale, shift, dinv, N, 64, 256);
    k_agg256<<<aggb, 256, 0, stream>>>((const float4*)bufC, dinv, rowptr, colv, (float4*)out, N);
    k_bnstat1<<<NBLK_STAT, 256, 0, stream>>>(out, part, N, 256);
    k_bnstat2<<<1, 256, 0, stream>>>(part, g3, be3, scale, shift, NBLK_STAT, 256, 1.0f / N);

    k_final<<<2048, 256, 0, stream>>>(out, x, scale, shift, N);
}

// Round 2
// 659.320 us; speedup vs baseline: 1.3226x; 1.3226x over previous
//
#include <hip/hip_runtime.h>
#include <hip/hip_bf16.h>

#define BN_EPS 1e-5f
#define NBLK_STAT 128

// ---------------- degree / CSR build ----------------

__global__ void k_degree(const int* __restrict__ dst, int* __restrict__ cnt, int E) {
    int e = blockIdx.x * blockDim.x + threadIdx.x;
    if (e < E) atomicAdd(&cnt[dst[e]], 1);
}

// hierarchical scan: (1) per-block reduce, (2) scan of block sums, (3) per-block rescan
__global__ __launch_bounds__(256) void k_scan1(const int* __restrict__ cnt,
                                               int* __restrict__ bsum, int n) {
    __shared__ int l[256];
    int i = blockIdx.x * 256 + threadIdx.x;
    l[threadIdx.x] = (i < n) ? cnt[i] : 0;
    __syncthreads();
    for (int off = 128; off > 0; off >>= 1) {
        if (threadIdx.x < off) l[threadIdx.x] += l[threadIdx.x + off];
        __syncthreads();
    }
    if (threadIdx.x == 0) bsum[blockIdx.x] = l[0];
}

__global__ __launch_bounds__(256) void k_scan2(const int* __restrict__ bsum,
                                               int* __restrict__ boff, int nblk) {
    __shared__ int l[256];
    int t = threadIdx.x;
    l[t] = (t < nblk) ? bsum[t] : 0;
    __syncthreads();
    for (int off = 1; off < 256; off <<= 1) {
        int v = l[t];
        int add = (t >= off) ? l[t - off] : 0;
        __syncthreads();
        l[t] = v + add;
        __syncthreads();
    }
    boff[t] = (t == 0) ? 0 : l[t - 1];  // exclusive
}

__global__ __launch_bounds__(256) void k_scan3(const int* __restrict__ cnt,
                                               const int* __restrict__ boff,
                                               int* __restrict__ rowptr,
                                               int* __restrict__ pos,
                                               float* __restrict__ dinv, int n, int E) {
    __shared__ int l[256];
    int t = threadIdx.x;
    int i = blockIdx.x * 256 + t;
    int c = (i < n) ? cnt[i] : 0;
    l[t] = c;
    __syncthreads();
    for (int off = 1; off < 256; off <<= 1) {
        int v = l[t];
        int add = (t >= off) ? l[t - off] : 0;
        __syncthreads();
        l[t] = v + add;
        __syncthreads();
    }
    if (i < n) {
        int excl = boff[blockIdx.x] + l[t] - c;  // exclusive within-block + block offset
        rowptr[i] = excl;
        pos[i] = excl;
        dinv[i] = rsqrtf((float)c + 1.0f);
    }
    if (blockIdx.x == 0 && t == 0) rowptr[n] = E;
}

__global__ void k_fill(const int* __restrict__ src, const int* __restrict__ dst,
                       int* __restrict__ pos, int* __restrict__ col, int E) {
    int e = blockIdx.x * blockDim.x + threadIdx.x;
    if (e < E) {
        int d = dst[e];
        int p = atomicAdd(&pos[d], 1);
        col[p] = src[e];
    }
}

// ---------------- GEMM: C[n,OUT] = transform(A[n,K]) @ W[K,OUT] ----------------
// transform (if scale != null): a = relu(a*scale[k] + shift[k])
// epilogue ×dinv[row] if dinv != null

__global__ __launch_bounds__(256) void k_gemm(const float* __restrict__ A,
                                              const float* __restrict__ W,
                                              float* __restrict__ C,
                                              const float* __restrict__ scale,
                                              const float* __restrict__ shift,
                                              const float* __restrict__ dinv,
                                              int n, int K, int OUT) {
    __shared__ float As[64][68];
    __shared__ float Ws[64][68];
    int row0 = blockIdx.x * 64;
    int col0 = blockIdx.y * 64;
    int tid = threadIdx.x;
    int tc = tid & 15;
    int tr = tid >> 4;
    float acc[4][4] = {{0.f}};

    for (int k0 = 0; k0 < K; k0 += 64) {
        for (int i = tid; i < 1024; i += 256) {
            int r = i >> 4;
            int c4 = (i & 15) << 2;
            int gr = row0 + r;
            float4 v = make_float4(0.f, 0.f, 0.f, 0.f);
            if (gr < n) v = *(const float4*)(A + (size_t)gr * K + (k0 + c4));
            if (scale) {
                const float4 sc = *(const float4*)(scale + k0 + c4);
                const float4 sh = *(const float4*)(shift + k0 + c4);
                v.x = fmaxf(v.x * sc.x + sh.x, 0.f);
                v.y = fmaxf(v.y * sc.y + sh.y, 0.f);
                v.z = fmaxf(v.z * sc.z + sh.z, 0.f);
                v.w = fmaxf(v.w * sc.w + sh.w, 0.f);
            }
            *(float4*)&As[r][c4] = v;
            float4 wv = *(const float4*)(W + (size_t)(k0 + r) * OUT + (col0 + c4));
            *(float4*)&Ws[r][c4] = wv;
        }
        __syncthreads();
        #pragma unroll
        for (int kk = 0; kk < 64; kk += 4) {
            float4 w0 = *(const float4*)&Ws[kk + 0][tc << 2];
            float4 w1 = *(const float4*)&Ws[kk + 1][tc << 2];
            float4 w2 = *(const float4*)&Ws[kk + 2][tc << 2];
            float4 w3 = *(const float4*)&Ws[kk + 3][tc << 2];
            #pragma unroll
            for (int i = 0; i < 4; ++i) {
                float4 a = *(const float4*)&As[(tr << 2) + i][kk];
                acc[i][0] += a.x * w0.x + a.y * w1.x + a.z * w2.x + a.w * w3.x;
                acc[i][1] += a.x * w0.y + a.y * w1.y + a.z * w2.y + a.w * w3.y;
                acc[i][2] += a.x * w0.z + a.y * w1.z + a.z * w2.z + a.w * w3.z;
                acc[i][3] += a.x * w0.w + a.y * w1.w + a.z * w2.w + a.w * w3.w;
            }
        }
        __syncthreads();
    }
    #pragma unroll
    for (int i = 0; i < 4; ++i) {
        int gr = row0 + (tr << 2) + i;
        if (gr >= n) continue;
        float dv = dinv ? dinv[gr] : 1.0f;
        float4 o = make_float4(acc[i][0] * dv, acc[i][1] * dv, acc[i][2] * dv, acc[i][3] * dv);
        *(float4*)(C + (size_t)gr * OUT + col0 + (tc << 2)) = o;
    }
}

// ---------------- aggregation (width 64): out[i] = dinv[i] * (Hs[i] + sum_{src} Hs[src]) ----------------

__global__ void k_agg64(const float* __restrict__ Hs, const float* __restrict__ dinv,
                        const int* __restrict__ rowptr, const int* __restrict__ col,
                        float* __restrict__ out, int n) {
    int node = (blockIdx.x * blockDim.x + threadIdx.x) >> 6;
    int lane = threadIdx.x & 63;
    if (node >= n) return;
    float s0 = Hs[(size_t)node * 64 + lane];
    float s1 = 0.f, s2 = 0.f, s3 = 0.f;
    int b = rowptr[node], e = rowptr[node + 1];
    int j = b;
    for (; j + 4 <= e; j += 4) {
        int i0 = col[j], i1 = col[j + 1], i2 = col[j + 2], i3 = col[j + 3];
        s0 += Hs[(size_t)i0 * 64 + lane];
        s1 += Hs[(size_t)i1 * 64 + lane];
        s2 += Hs[(size_t)i2 * 64 + lane];
        s3 += Hs[(size_t)i3 * 64 + lane];
    }
    for (; j < e; ++j) s0 += Hs[(size_t)col[j] * 64 + lane];
    out[(size_t)node * 64 + lane] = dinv[node] * ((s0 + s1) + (s2 + s3));
}

// ---------------- elementwise: out = relu(in*scale[c] + shift[c]) * dinv[row]  (width 64) ----------------

__global__ void k_transform64(const float* __restrict__ in, float* __restrict__ out,
                              const float* __restrict__ scale, const float* __restrict__ shift,
                              const float* __restrict__ dinv, int n) {
    int idx = blockIdx.x * blockDim.x + threadIdx.x;
    int total = n * 16;  // float4 count
    for (int i = idx; i < total; i += gridDim.x * blockDim.x) {
        float4 v = *(const float4*)(in + (size_t)i * 4);
        int c4 = (i & 15) << 2;
        int row = i >> 4;
        float4 sc = *(const float4*)(scale + c4);
        float4 sh = *(const float4*)(shift + c4);
        float dv = dinv[row];
        v.x = fmaxf(v.x * sc.x + sh.x, 0.f) * dv;
        v.y = fmaxf(v.y * sc.y + sh.y, 0.f) * dv;
        v.z = fmaxf(v.z * sc.z + sh.z, 0.f) * dv;
        v.w = fmaxf(v.w * sc.w + sh.w, 0.f) * dv;
        *(float4*)(out + (size_t)i * 4) = v;
    }
}

// ---------------- BN statistics ----------------

__global__ __launch_bounds__(256) void k_bnstat1(const float* __restrict__ X,
                                                 float* __restrict__ part, int n, int W) {
    int lanes = 256 / W;
    int c = threadIdx.x & (W - 1);
    int rsub = threadIdx.x / W;
    int rows_per_blk = (n + gridDim.x - 1) / gridDim.x;
    int r0 = blockIdx.x * rows_per_blk;
    int r1 = min(r0 + rows_per_blk, n);
    float s = 0.f, s2 = 0.f;
    for (int r = r0 + rsub; r < r1; r += lanes) {
        float v = X[(size_t)r * W + c];
        s += v;
        s2 += v * v;
    }
    __shared__ float ls[256], ls2[256];
    ls[threadIdx.x] = s;
    ls2[threadIdx.x] = s2;
    __syncthreads();
    if (rsub == 0) {
        for (int k = 1; k < lanes; ++k) {
            s += ls[k * W + c];
            s2 += ls2[k * W + c];
        }
        part[(size_t)blockIdx.x * W + c] = s;
        part[(size_t)(gridDim.x + blockIdx.x) * W + c] = s2;
    }
}

__global__ void k_bnstat2(const float* __restrict__ part, const float* __restrict__ g,
                          const float* __restrict__ be, float* __restrict__ scale,
                          float* __restrict__ shift, int nblk, int W, float inv_n) {
    int c = blockIdx.x * blockDim.x + threadIdx.x;
    if (c >= W) return;
    float s = 0.f, s2 = 0.f;
    for (int b = 0; b < nblk; ++b) {
        s += part[(size_t)b * W + c];
        s2 += part[(size_t)(nblk + b) * W + c];
    }
    float m = s * inv_n;
    float v = s2 * inv_n - m * m;
    float sc = g[c] * rsqrtf(v + BN_EPS);
    scale[c] = sc;
    shift[c] = be[c] - m * sc;
}

// ---------------- final: out = relu(out*scale[c] + shift[c] + x) (in place, W=256) ----------------

__global__ void k_final(float* __restrict__ out, const float* __restrict__ x,
                        const float* __restrict__ scale, const float* __restrict__ shift, int n) {
    int idx = blockIdx.x * blockDim.x + threadIdx.x;
    int total = n * 64;  // float4 count
    for (int i = idx; i < total; i += gridDim.x * blockDim.x) {
        float4 v = *(const float4*)(out + (size_t)i * 4);
        float4 xv = *(const float4*)(x + (size_t)i * 4);
        int c4 = (i & 63) << 2;
        float4 sc = *(const float4*)(scale + c4);
        float4 sh = *(const float4*)(shift + c4);
        v.x = fmaxf(v.x * sc.x + sh.x + xv.x, 0.f);
        v.y = fmaxf(v.y * sc.y + sh.y + xv.y, 0.f);
        v.z = fmaxf(v.z * sc.z + sh.z + xv.z, 0.f);
        v.w = fmaxf(v.w * sc.w + sh.w + xv.w, 0.f);
        *(float4*)(out + (size_t)i * 4) = v;
    }
}

// ---------------- launch ----------------

extern "C" void kernel_launch(void* const* d_in, const int* in_sizes, int n_in,
                              void* d_out, int out_size, void* d_ws, size_t ws_size,
                              hipStream_t stream) {
    const float* x   = (const float*)d_in[0];
    const int*   ei  = (const int*)d_in[1];
    const int    N   = in_sizes[2];
    const int    E   = in_sizes[1] / 2;
    const float* W1  = (const float*)d_in[3];
    const float* g1  = (const float*)d_in[5];
    const float* be1 = (const float*)d_in[6];
    const float* W2  = (const float*)d_in[7];
    const float* g2  = (const float*)d_in[9];
    const float* be2 = (const float*)d_in[10];
    const float* W3  = (const float*)d_in[11];
    const float* g3  = (const float*)d_in[13];
    const float* be3 = (const float*)d_in[14];
    float* out = (float*)d_out;

    char* p = (char*)d_ws;
    auto alloc = [&](size_t bytes) {
        char* q = p;
        p += (bytes + 255) & ~(size_t)255;
        return q;
    };
    int*   cnt    = (int*)alloc((size_t)N * 4);
    int*   rowptr = (int*)alloc((size_t)(N + 1) * 4);
    int*   pos    = (int*)alloc((size_t)N * 4);
    int*   colv   = (int*)alloc((size_t)E * 4);
    float* dinv   = (float*)alloc((size_t)N * 4);
    int*   bsum   = (int*)alloc(256 * 4);
    int*   boff   = (int*)alloc(256 * 4);
    float* bufA   = (float*)alloc((size_t)N * 64 * 4);
    float* bufB   = (float*)alloc((size_t)N * 64 * 4);
    float* part   = (float*)alloc((size_t)2 * NBLK_STAT * 256 * 4);
    float* scale  = (float*)alloc(256 * 4);
    float* shift  = (float*)alloc(256 * 4);

    const int* srcp = ei;
    const int* dstp = ei + E;

    hipMemsetAsync(cnt, 0, (size_t)N * 4, stream);
    int eb = (E + 255) / 256;
    int nscan = (N + 255) / 256;
    k_degree<<<eb, 256, 0, stream>>>(dstp, cnt, E);
    k_scan1<<<nscan, 256, 0, stream>>>(cnt, bsum, N);
    k_scan2<<<1, 256, 0, stream>>>(bsum, boff, nscan);
    k_scan3<<<nscan, 256, 0, stream>>>(cnt, boff, rowptr, pos, dinv, N, E);
    k_fill<<<eb, 256, 0, stream>>>(srcp, dstp, pos, colv, E);

    dim3 gemm_g((N + 63) / 64, 1);
    dim3 gemm3_g((N + 63) / 64, 4);
    int aggb = (N * 64 + 255) / 256;  // one wave per node
    int ewb64 = 2048;

    // conv1: Hs1 = (x @ W1) * dinv   -> agg -> bufB (pre-BN)
    k_gemm<<<gemm_g, 256, 0, stream>>>(x, W1, bufA, nullptr, nullptr, dinv, N, 256, 64);
    k_agg64<<<aggb, 256, 0, stream>>>(bufA, dinv, rowptr, colv, bufB, N);
    k_bnstat1<<<NBLK_STAT, 256, 0, stream>>>(bufB, part, N, 64);
    k_bnstat2<<<1, 64, 0, stream>>>(part, g1, be1, scale, shift, NBLK_STAT, 64, 1.0f / N);

    // conv2: BN1+ReLU fused into GEMM A-load; epilogue ×dinv; agg -> bufB (pre-BN)
    k_gemm<<<gemm_g, 256, 0, stream>>>(bufB, W2, bufA, scale, shift, dinv, N, 64, 64);
    k_agg64<<<aggb, 256, 0, stream>>>(bufA, dinv, rowptr, colv, bufB, N);
    k_bnstat1<<<NBLK_STAT, 256, 0, stream>>>(bufB, part, N, 64);
    k_bnstat2<<<1, 64, 0, stream>>>(part, g2, be2, scale, shift, NBLK_STAT, 64, 1.0f / N);

    // conv3 (agg-first): bufA = relu(BN2(bufB))*dinv; agg64 -> bufB; out = bufB @ W3
    k_transform64<<<ewb64, 256, 0, stream>>>(bufB, bufA, scale, shift, dinv, N);
    k_agg64<<<aggb, 256, 0, stream>>>(bufA, dinv, rowptr, colv, bufB, N);
    k_gemm<<<gemm3_g, 256, 0, stream>>>(bufB, W3, out, nullptr, nullptr, nullptr, N, 64, 256);
    k_bnstat1<<<NBLK_STAT, 256, 0, stream>>>(out, part, N, 256);
    k_bnstat2<<<1, 256, 0, stream>>>(part, g3, be3, scale, shift, NBLK_STAT, 256, 1.0f / N);

    k_final<<<2048, 256, 0, stream>>>(out, x, scale, shift, N);
}

// Round 3
// 472.627 us; speedup vs baseline: 1.8450x; 1.3950x over previous
//
#include <hip/hip_runtime.h>
#include <hip/hip_bf16.h>

#define BN_EPS 1e-5f
#define NBLK_STAT 256

// ---------------- degree / CSR build ----------------

__global__ void k_degree(const int* __restrict__ dst, int* __restrict__ cnt, int E) {
    int e = blockIdx.x * blockDim.x + threadIdx.x;
    if (e < E) atomicAdd(&cnt[dst[e]], 1);
}

// hierarchical scan: (1) per-block reduce, (2) scan of block sums, (3) per-block rescan
__global__ __launch_bounds__(256) void k_scan1(const int* __restrict__ cnt,
                                               int* __restrict__ bsum, int n) {
    __shared__ int l[256];
    int i = blockIdx.x * 256 + threadIdx.x;
    l[threadIdx.x] = (i < n) ? cnt[i] : 0;
    __syncthreads();
    for (int off = 128; off > 0; off >>= 1) {
        if (threadIdx.x < off) l[threadIdx.x] += l[threadIdx.x + off];
        __syncthreads();
    }
    if (threadIdx.x == 0) bsum[blockIdx.x] = l[0];
}

__global__ __launch_bounds__(256) void k_scan2(const int* __restrict__ bsum,
                                               int* __restrict__ boff, int nblk) {
    __shared__ int l[256];
    int t = threadIdx.x;
    l[t] = (t < nblk) ? bsum[t] : 0;
    __syncthreads();
    for (int off = 1; off < 256; off <<= 1) {
        int v = l[t];
        int add = (t >= off) ? l[t - off] : 0;
        __syncthreads();
        l[t] = v + add;
        __syncthreads();
    }
    boff[t] = (t == 0) ? 0 : l[t - 1];  // exclusive
}

__global__ __launch_bounds__(256) void k_scan3(const int* __restrict__ cnt,
                                               const int* __restrict__ boff,
                                               int* __restrict__ rowptr,
                                               int* __restrict__ pos,
                                               float* __restrict__ dinv, int n, int E) {
    __shared__ int l[256];
    int t = threadIdx.x;
    int i = blockIdx.x * 256 + t;
    int c = (i < n) ? cnt[i] : 0;
    l[t] = c;
    __syncthreads();
    for (int off = 1; off < 256; off <<= 1) {
        int v = l[t];
        int add = (t >= off) ? l[t - off] : 0;
        __syncthreads();
        l[t] = v + add;
        __syncthreads();
    }
    if (i < n) {
        int excl = boff[blockIdx.x] + l[t] - c;
        rowptr[i] = excl;
        pos[i] = excl;
        dinv[i] = rsqrtf((float)c + 1.0f);
    }
    if (blockIdx.x == 0 && t == 0) rowptr[n] = E;
}

__global__ void k_fill(const int* __restrict__ src, const int* __restrict__ dst,
                       int* __restrict__ pos, int* __restrict__ col, int E) {
    int e = blockIdx.x * blockDim.x + threadIdx.x;
    if (e < E) {
        int d = dst[e];
        int p = atomicAdd(&pos[d], 1);
        col[p] = src[e];
    }
}

// ---------------- GEMM: C[n,OUT] = transform(A[n,K]) @ W[K,OUT] ----------------

__global__ __launch_bounds__(256) void k_gemm(const float* __restrict__ A,
                                              const float* __restrict__ W,
                                              float* __restrict__ C,
                                              const float* __restrict__ scale,
                                              const float* __restrict__ shift,
                                              const float* __restrict__ dinv,
                                              int n, int K, int OUT) {
    __shared__ float As[64][68];
    __shared__ float Ws[64][68];
    int row0 = blockIdx.x * 64;
    int col0 = blockIdx.y * 64;
    int tid = threadIdx.x;
    int tc = tid & 15;
    int tr = tid >> 4;
    float acc[4][4] = {{0.f}};

    for (int k0 = 0; k0 < K; k0 += 64) {
        for (int i = tid; i < 1024; i += 256) {
            int r = i >> 4;
            int c4 = (i & 15) << 2;
            int gr = row0 + r;
            float4 v = make_float4(0.f, 0.f, 0.f, 0.f);
            if (gr < n) v = *(const float4*)(A + (size_t)gr * K + (k0 + c4));
            if (scale) {
                const float4 sc = *(const float4*)(scale + k0 + c4);
                const float4 sh = *(const float4*)(shift + k0 + c4);
                v.x = fmaxf(v.x * sc.x + sh.x, 0.f);
                v.y = fmaxf(v.y * sc.y + sh.y, 0.f);
                v.z = fmaxf(v.z * sc.z + sh.z, 0.f);
                v.w = fmaxf(v.w * sc.w + sh.w, 0.f);
            }
            *(float4*)&As[r][c4] = v;
            float4 wv = *(const float4*)(W + (size_t)(k0 + r) * OUT + (col0 + c4));
            *(float4*)&Ws[r][c4] = wv;
        }
        __syncthreads();
        #pragma unroll
        for (int kk = 0; kk < 64; kk += 4) {
            float4 w0 = *(const float4*)&Ws[kk + 0][tc << 2];
            float4 w1 = *(const float4*)&Ws[kk + 1][tc << 2];
            float4 w2 = *(const float4*)&Ws[kk + 2][tc << 2];
            float4 w3 = *(const float4*)&Ws[kk + 3][tc << 2];
            #pragma unroll
            for (int i = 0; i < 4; ++i) {
                float4 a = *(const float4*)&As[(tr << 2) + i][kk];
                acc[i][0] += a.x * w0.x + a.y * w1.x + a.z * w2.x + a.w * w3.x;
                acc[i][1] += a.x * w0.y + a.y * w1.y + a.z * w2.y + a.w * w3.y;
                acc[i][2] += a.x * w0.z + a.y * w1.z + a.z * w2.z + a.w * w3.z;
                acc[i][3] += a.x * w0.w + a.y * w1.w + a.z * w2.w + a.w * w3.w;
            }
        }
        __syncthreads();
    }
    #pragma unroll
    for (int i = 0; i < 4; ++i) {
        int gr = row0 + (tr << 2) + i;
        if (gr >= n) continue;
        float dv = dinv ? dinv[gr] : 1.0f;
        float4 o = make_float4(acc[i][0] * dv, acc[i][1] * dv, acc[i][2] * dv, acc[i][3] * dv);
        *(float4*)(C + (size_t)gr * OUT + col0 + (tc << 2)) = o;
    }
}

// ---------------- aggregation (width 64) ----------------
// plain (scale==null):  out[i] = dinv[i] * (Hs[i] + sum_{src} Hs[src])        (Hs already ×dinv)
// fused (scale!=null):  T(v,j) = relu(v*scale[c]+shift[c]) * dinv[j]
//                       out[i] = dinv[i] * (T(Hs[i],i) + sum_{src} T(Hs[src],src))

__global__ void k_agg64(const float* __restrict__ Hs, const float* __restrict__ dinv,
                        const int* __restrict__ rowptr, const int* __restrict__ col,
                        float* __restrict__ out, int n,
                        const float* __restrict__ scale, const float* __restrict__ shift) {
    int node = (blockIdx.x * blockDim.x + threadIdx.x) >> 6;
    int lane = threadIdx.x & 63;
    if (node >= n) return;
    int b = rowptr[node], e = rowptr[node + 1];
    if (scale) {
        float sc = scale[lane], sh = shift[lane];
        float s0 = fmaxf(Hs[(size_t)node * 64 + lane] * sc + sh, 0.f) * dinv[node];
        float s1 = 0.f, s2 = 0.f, s3 = 0.f;
        int j = b;
        for (; j + 4 <= e; j += 4) {
            int i0 = col[j], i1 = col[j + 1], i2 = col[j + 2], i3 = col[j + 3];
            s0 += fmaxf(Hs[(size_t)i0 * 64 + lane] * sc + sh, 0.f) * dinv[i0];
            s1 += fmaxf(Hs[(size_t)i1 * 64 + lane] * sc + sh, 0.f) * dinv[i1];
            s2 += fmaxf(Hs[(size_t)i2 * 64 + lane] * sc + sh, 0.f) * dinv[i2];
            s3 += fmaxf(Hs[(size_t)i3 * 64 + lane] * sc + sh, 0.f) * dinv[i3];
        }
        for (; j < e; ++j) {
            int i0 = col[j];
            s0 += fmaxf(Hs[(size_t)i0 * 64 + lane] * sc + sh, 0.f) * dinv[i0];
        }
        out[(size_t)node * 64 + lane] = dinv[node] * ((s0 + s1) + (s2 + s3));
    } else {
        float s0 = Hs[(size_t)node * 64 + lane];
        float s1 = 0.f, s2 = 0.f, s3 = 0.f;
        int j = b;
        for (; j + 4 <= e; j += 4) {
            int i0 = col[j], i1 = col[j + 1], i2 = col[j + 2], i3 = col[j + 3];
            s0 += Hs[(size_t)i0 * 64 + lane];
            s1 += Hs[(size_t)i1 * 64 + lane];
            s2 += Hs[(size_t)i2 * 64 + lane];
            s3 += Hs[(size_t)i3 * 64 + lane];
        }
        for (; j < e; ++j) s0 += Hs[(size_t)col[j] * 64 + lane];
        out[(size_t)node * 64 + lane] = dinv[node] * ((s0 + s1) + (s2 + s3));
    }
}

// ---------------- BN statistics (vectorized, high-occupancy) ----------------
// part[b*W + c] = partial sum, part[(nblk + b)*W + c] = partial sumsq

__global__ __launch_bounds__(256) void k_bnstat1(const float* __restrict__ X,
                                                 float* __restrict__ part, int n, int W) {
    int cols4 = W >> 2;               // float4 per row (16 or 64)
    int c4 = threadIdx.x & (cols4 - 1);
    int rsub = threadIdx.x / cols4;
    int lanes = 256 / cols4;          // rows in parallel (16 or 4)
    int nrg = (n + lanes - 1) / lanes;
    float4 s = make_float4(0.f, 0.f, 0.f, 0.f);
    float4 s2 = make_float4(0.f, 0.f, 0.f, 0.f);
    for (int rg = blockIdx.x; rg < nrg; rg += gridDim.x) {
        int r = rg * lanes + rsub;
        if (r < n) {
            float4 v = *(const float4*)(X + (size_t)r * W + (c4 << 2));
            s.x += v.x; s.y += v.y; s.z += v.z; s.w += v.w;
            s2.x += v.x * v.x; s2.y += v.y * v.y; s2.z += v.z * v.z; s2.w += v.w * v.w;
        }
    }
    __shared__ float4 ls[256], ls2[256];
    ls[threadIdx.x] = s;
    ls2[threadIdx.x] = s2;
    __syncthreads();
    for (int off = lanes >> 1; off > 0; off >>= 1) {
        if (rsub < off) {
            int i = threadIdx.x, j = threadIdx.x + off * cols4;
            float4 a = ls[i], b = ls[j];
            a.x += b.x; a.y += b.y; a.z += b.z; a.w += b.w;
            ls[i] = a;
            float4 a2 = ls2[i], b2 = ls2[j];
            a2.x += b2.x; a2.y += b2.y; a2.z += b2.z; a2.w += b2.w;
            ls2[i] = a2;
        }
        __syncthreads();
    }
    if (rsub == 0) {
        *(float4*)(part + (size_t)blockIdx.x * W + (c4 << 2)) = ls[c4];
        *(float4*)(part + (size_t)(gridDim.x + blockIdx.x) * W + (c4 << 2)) = ls2[c4];
    }
}

__global__ __launch_bounds__(1024) void k_bnstat2(const float* __restrict__ part,
                                                  const float* __restrict__ g,
                                                  const float* __restrict__ be,
                                                  float* __restrict__ scale,
                                                  float* __restrict__ shift,
                                                  int nblk, int W, float inv_n) {
    int t = threadIdx.x;
    int c = t & (W - 1);
    int q = t / W;
    int nq = 1024 / W;          // 16 (W=64) or 4 (W=256)
    int per = nblk / nq;
    float s = 0.f, s2 = 0.f;
    for (int b = q * per; b < (q + 1) * per; ++b) {
        s  += part[(size_t)b * W + c];
        s2 += part[(size_t)(nblk + b) * W + c];
    }
    __shared__ float ls[1024], ls2[1024];
    ls[t] = s;
    ls2[t] = s2;
    __syncthreads();
    if (q == 0) {
        for (int k = 1; k < nq; ++k) {
            s += ls[k * W + c];
            s2 += ls2[k * W + c];
        }
        float m = s * inv_n;
        float v = s2 * inv_n - m * m;
        float sc = g[c] * rsqrtf(v + BN_EPS);
        scale[c] = sc;
        shift[c] = be[c] - m * sc;
    }
}

// ---------------- final: out = relu(out*scale[c] + shift[c] + x) (in place, W=256) ----------------

__global__ void k_final(float* __restrict__ out, const float* __restrict__ x,
                        const float* __restrict__ scale, const float* __restrict__ shift, int n) {
    int idx = blockIdx.x * blockDim.x + threadIdx.x;
    int total = n * 64;  // float4 count
    for (int i = idx; i < total; i += gridDim.x * blockDim.x) {
        float4 v = *(const float4*)(out + (size_t)i * 4);
        float4 xv = *(const float4*)(x + (size_t)i * 4);
        int c4 = (i & 63) << 2;
        float4 sc = *(const float4*)(scale + c4);
        float4 sh = *(const float4*)(shift + c4);
        v.x = fmaxf(v.x * sc.x + sh.x + xv.x, 0.f);
        v.y = fmaxf(v.y * sc.y + sh.y + xv.y, 0.f);
        v.z = fmaxf(v.z * sc.z + sh.z + xv.z, 0.f);
        v.w = fmaxf(v.w * sc.w + sh.w + xv.w, 0.f);
        *(float4*)(out + (size_t)i * 4) = v;
    }
}

// ---------------- launch ----------------

extern "C" void kernel_launch(void* const* d_in, const int* in_sizes, int n_in,
                              void* d_out, int out_size, void* d_ws, size_t ws_size,
                              hipStream_t stream) {
    const float* x   = (const float*)d_in[0];
    const int*   ei  = (const int*)d_in[1];
    const int    N   = in_sizes[2];
    const int    E   = in_sizes[1] / 2;
    const float* W1  = (const float*)d_in[3];
    const float* g1  = (const float*)d_in[5];
    const float* be1 = (const float*)d_in[6];
    const float* W2  = (const float*)d_in[7];
    const float* g2  = (const float*)d_in[9];
    const float* be2 = (const float*)d_in[10];
    const float* W3  = (const float*)d_in[11];
    const float* g3  = (const float*)d_in[13];
    const float* be3 = (const float*)d_in[14];
    float* out = (float*)d_out;

    char* p = (char*)d_ws;
    auto alloc = [&](size_t bytes) {
        char* q = p;
        p += (bytes + 255) & ~(size_t)255;
        return q;
    };
    int*   cnt    = (int*)alloc((size_t)N * 4);
    int*   rowptr = (int*)alloc((size_t)(N + 1) * 4);
    int*   pos    = (int*)alloc((size_t)N * 4);
    int*   colv   = (int*)alloc((size_t)E * 4);
    float* dinv   = (float*)alloc((size_t)N * 4);
    int*   bsum   = (int*)alloc(256 * 4);
    int*   boff   = (int*)alloc(256 * 4);
    float* bufA   = (float*)alloc((size_t)N * 64 * 4);
    float* bufB   = (float*)alloc((size_t)N * 64 * 4);
    float* part   = (float*)alloc((size_t)2 * NBLK_STAT * 256 * 4);
    float* scale  = (float*)alloc(256 * 4);
    float* shift  = (float*)alloc(256 * 4);

    const int* srcp = ei;
    const int* dstp = ei + E;

    hipMemsetAsync(cnt, 0, (size_t)N * 4, stream);
    int eb = (E + 255) / 256;
    int nscan = (N + 255) / 256;
    k_degree<<<eb, 256, 0, stream>>>(dstp, cnt, E);
    k_scan1<<<nscan, 256, 0, stream>>>(cnt, bsum, N);
    k_scan2<<<1, 256, 0, stream>>>(bsum, boff, nscan);
    k_scan3<<<nscan, 256, 0, stream>>>(cnt, boff, rowptr, pos, dinv, N, E);
    k_fill<<<eb, 256, 0, stream>>>(srcp, dstp, pos, colv, E);

    dim3 gemm_g((N + 63) / 64, 1);
    dim3 gemm3_g((N + 63) / 64, 4);
    int aggb = (N * 64 + 255) / 256;  // one wave per node

    // conv1: Hs1 = (x @ W1) * dinv   -> agg -> bufB (pre-BN)
    k_gemm<<<gemm_g, 256, 0, stream>>>(x, W1, bufA, nullptr, nullptr, dinv, N, 256, 64);
    k_agg64<<<aggb, 256, 0, stream>>>(bufA, dinv, rowptr, colv, bufB, N, nullptr, nullptr);
    k_bnstat1<<<NBLK_STAT, 256, 0, stream>>>(bufB, part, N, 64);
    k_bnstat2<<<1, 1024, 0, stream>>>(part, g1, be1, scale, shift, NBLK_STAT, 64, 1.0f / N);

    // conv2: BN1+ReLU fused into GEMM A-load; epilogue ×dinv; agg -> bufB (pre-BN)
    k_gemm<<<gemm_g, 256, 0, stream>>>(bufB, W2, bufA, scale, shift, dinv, N, 64, 64);
    k_agg64<<<aggb, 256, 0, stream>>>(bufA, dinv, rowptr, colv, bufB, N, nullptr, nullptr);
    k_bnstat1<<<NBLK_STAT, 256, 0, stream>>>(bufB, part, N, 64);
    k_bnstat2<<<1, 1024, 0, stream>>>(part, g2, be2, scale, shift, NBLK_STAT, 64, 1.0f / N);

    // conv3 (agg-first, BN2+ReLU+dinv fused into gather): bufB -> bufA; out = bufA @ W3
    k_agg64<<<aggb, 256, 0, stream>>>(bufB, dinv, rowptr, colv, bufA, N, scale, shift);
    k_gemm<<<gemm3_g, 256, 0, stream>>>(bufA, W3, out, nullptr, nullptr, nullptr, N, 64, 256);
    k_bnstat1<<<NBLK_STAT, 256, 0, stream>>>(out, part, N, 256);
    k_bnstat2<<<1, 1024, 0, stream>>>(part, g3, be3, scale, shift, NBLK_STAT, 256, 1.0f / N);

    k_final<<<2048, 256, 0, stream>>>(out, x, scale, shift, N);
}

// Round 4
// 460.122 us; speedup vs baseline: 1.8951x; 1.0272x over previous
//
#include <hip/hip_runtime.h>
#include <hip/hip_bf16.h>

#define BN_EPS 1e-5f
#define NBLK_STAT 256

// ---------------- degree / CSR build ----------------

__global__ void k_degree(const int* __restrict__ dst, int* __restrict__ cnt, int E) {
    int e = blockIdx.x * blockDim.x + threadIdx.x;
    if (e < E) atomicAdd(&cnt[dst[e]], 1);
}

__global__ __launch_bounds__(256) void k_scan1(const int* __restrict__ cnt,
                                               int* __restrict__ bsum, int n) {
    __shared__ int l[256];
    int i = blockIdx.x * 256 + threadIdx.x;
    l[threadIdx.x] = (i < n) ? cnt[i] : 0;
    __syncthreads();
    for (int off = 128; off > 0; off >>= 1) {
        if (threadIdx.x < off) l[threadIdx.x] += l[threadIdx.x + off];
        __syncthreads();
    }
    if (threadIdx.x == 0) bsum[blockIdx.x] = l[0];
}

__global__ __launch_bounds__(256) void k_scan2(const int* __restrict__ bsum,
                                               int* __restrict__ boff, int nblk) {
    __shared__ int l[256];
    int t = threadIdx.x;
    l[t] = (t < nblk) ? bsum[t] : 0;
    __syncthreads();
    for (int off = 1; off < 256; off <<= 1) {
        int v = l[t];
        int add = (t >= off) ? l[t - off] : 0;
        __syncthreads();
        l[t] = v + add;
        __syncthreads();
    }
    boff[t] = (t == 0) ? 0 : l[t - 1];  // exclusive
}

__global__ __launch_bounds__(256) void k_scan3(const int* __restrict__ cnt,
                                               const int* __restrict__ boff,
                                               int* __restrict__ rowptr,
                                               int* __restrict__ pos,
                                               float* __restrict__ dinv, int n, int E) {
    __shared__ int l[256];
    int t = threadIdx.x;
    int i = blockIdx.x * 256 + t;
    int c = (i < n) ? cnt[i] : 0;
    l[t] = c;
    __syncthreads();
    for (int off = 1; off < 256; off <<= 1) {
        int v = l[t];
        int add = (t >= off) ? l[t - off] : 0;
        __syncthreads();
        l[t] = v + add;
        __syncthreads();
    }
    if (i < n) {
        int excl = boff[blockIdx.x] + l[t] - c;
        rowptr[i] = excl;
        pos[i] = excl;
        dinv[i] = rsqrtf((float)c + 1.0f);
    }
    if (blockIdx.x == 0 && t == 0) rowptr[n] = E;
}

__global__ void k_fill(const int* __restrict__ src, const int* __restrict__ dst,
                       int* __restrict__ pos, int* __restrict__ col, int E) {
    int e = blockIdx.x * blockDim.x + threadIdx.x;
    if (e < E) {
        int d = dst[e];
        int p = atomicAdd(&pos[d], 1);
        col[p] = src[e];
    }
}

// ---------------- GEMM: C[n,OUT] = transform(A[n,K]) @ W[K,OUT] ----------------
// transform (if scale != null): a = relu(a*scale[k] + shift[k])
// epilogue ×dinv[row] if dinv != null
// Pipelined: BK=32 k-tiles, A/W LDS double-buffered via register prefetch,
// one barrier per k-tile. 64 rows × 64 cols per block, 256 threads, 4×4 acc.

__global__ __launch_bounds__(256) void k_gemm(const float* __restrict__ A,
                                              const float* __restrict__ W,
                                              float* __restrict__ C,
                                              const float* __restrict__ scale,
                                              const float* __restrict__ shift,
                                              const float* __restrict__ dinv,
                                              int n, int K, int OUT) {
    __shared__ float As[2][64][36];   // 64 rows x 32 k (+4 pad)
    __shared__ float Ws[2][32][68];   // 32 k x 64 cols (+4 pad)
    const int row0 = blockIdx.x * 64;
    const int col0 = blockIdx.y * 64;
    const int tid = threadIdx.x;
    const int tc = tid & 15;          // output col quad
    const int tr = tid >> 4;          // output row quad
    const int aLr = tid >> 3;         // A stage: row 0..31 (and +32)
    const int aLc = (tid & 7) << 2;   // A stage: k offset 0..28
    const int wLr = tid >> 4;         // W stage: k row 0..15 (and +16)
    const int wLc = (tid & 15) << 2;  // W stage: col offset 0..60
    const int NT = K >> 5;

    float4 pa0, pa1, pw0, pw1;
    float acc[4][4] = {{0.f}};

#define PREFETCH(k0)                                                               \
    {                                                                              \
        int gr0 = row0 + aLr;                                                      \
        int gr1 = gr0 + 32;                                                        \
        pa0 = make_float4(0.f, 0.f, 0.f, 0.f);                                     \
        pa1 = make_float4(0.f, 0.f, 0.f, 0.f);                                     \
        if (gr0 < n) pa0 = *(const float4*)(A + (size_t)gr0 * K + (k0) + aLc);     \
        if (gr1 < n) pa1 = *(const float4*)(A + (size_t)gr1 * K + (k0) + aLc);     \
        if (scale) {                                                               \
            float4 sc = *(const float4*)(scale + (k0) + aLc);                      \
            float4 sh = *(const float4*)(shift + (k0) + aLc);                      \
            pa0.x = fmaxf(pa0.x * sc.x + sh.x, 0.f);                               \
            pa0.y = fmaxf(pa0.y * sc.y + sh.y, 0.f);                               \
            pa0.z = fmaxf(pa0.z * sc.z + sh.z, 0.f);                               \
            pa0.w = fmaxf(pa0.w * sc.w + sh.w, 0.f);                               \
            pa1.x = fmaxf(pa1.x * sc.x + sh.x, 0.f);                               \
            pa1.y = fmaxf(pa1.y * sc.y + sh.y, 0.f);                               \
            pa1.z = fmaxf(pa1.z * sc.z + sh.z, 0.f);                               \
            pa1.w = fmaxf(pa1.w * sc.w + sh.w, 0.f);                               \
        }                                                                          \
        pw0 = *(const float4*)(W + (size_t)((k0) + wLr) * OUT + col0 + wLc);       \
        pw1 = *(const float4*)(W + (size_t)((k0) + wLr + 16) * OUT + col0 + wLc);  \
    }

#define STORE(b)                                      \
    {                                                 \
        *(float4*)&As[b][aLr][aLc] = pa0;             \
        *(float4*)&As[b][aLr + 32][aLc] = pa1;        \
        *(float4*)&Ws[b][wLr][wLc] = pw0;             \
        *(float4*)&Ws[b][wLr + 16][wLc] = pw1;        \
    }

    PREFETCH(0)
    STORE(0)
    __syncthreads();

    for (int t = 0; t < NT; ++t) {
        int buf = t & 1;
        if (t + 1 < NT) PREFETCH((t + 1) << 5)
        #pragma unroll
        for (int kk = 0; kk < 32; kk += 4) {
            float4 w0 = *(const float4*)&Ws[buf][kk + 0][tc << 2];
            float4 w1 = *(const float4*)&Ws[buf][kk + 1][tc << 2];
            float4 w2 = *(const float4*)&Ws[buf][kk + 2][tc << 2];
            float4 w3 = *(const float4*)&Ws[buf][kk + 3][tc << 2];
            #pragma unroll
            for (int i = 0; i < 4; ++i) {
                float4 a = *(const float4*)&As[buf][(tr << 2) + i][kk];
                acc[i][0] += a.x * w0.x + a.y * w1.x + a.z * w2.x + a.w * w3.x;
                acc[i][1] += a.x * w0.y + a.y * w1.y + a.z * w2.y + a.w * w3.y;
                acc[i][2] += a.x * w0.z + a.y * w1.z + a.z * w2.z + a.w * w3.z;
                acc[i][3] += a.x * w0.w + a.y * w1.w + a.z * w2.w + a.w * w3.w;
            }
        }
        if (t + 1 < NT) {
            STORE(buf ^ 1)
            __syncthreads();
        }
    }
#undef PREFETCH
#undef STORE

    #pragma unroll
    for (int i = 0; i < 4; ++i) {
        int gr = row0 + (tr << 2) + i;
        if (gr >= n) continue;
        float dv = dinv ? dinv[gr] : 1.0f;
        float4 o = make_float4(acc[i][0] * dv, acc[i][1] * dv, acc[i][2] * dv, acc[i][3] * dv);
        *(float4*)(C + (size_t)gr * OUT + col0 + (tc << 2)) = o;
    }
}

// ---------------- aggregation (width 64) ----------------

__global__ void k_agg64(const float* __restrict__ Hs, const float* __restrict__ dinv,
                        const int* __restrict__ rowptr, const int* __restrict__ col,
                        float* __restrict__ out, int n,
                        const float* __restrict__ scale, const float* __restrict__ shift) {
    int node = (blockIdx.x * blockDim.x + threadIdx.x) >> 6;
    int lane = threadIdx.x & 63;
    if (node >= n) return;
    int b = rowptr[node], e = rowptr[node + 1];
    if (scale) {
        float sc = scale[lane], sh = shift[lane];
        float s0 = fmaxf(Hs[(size_t)node * 64 + lane] * sc + sh, 0.f) * dinv[node];
        float s1 = 0.f, s2 = 0.f, s3 = 0.f;
        int j = b;
        for (; j + 4 <= e; j += 4) {
            int i0 = col[j], i1 = col[j + 1], i2 = col[j + 2], i3 = col[j + 3];
            s0 += fmaxf(Hs[(size_t)i0 * 64 + lane] * sc + sh, 0.f) * dinv[i0];
            s1 += fmaxf(Hs[(size_t)i1 * 64 + lane] * sc + sh, 0.f) * dinv[i1];
            s2 += fmaxf(Hs[(size_t)i2 * 64 + lane] * sc + sh, 0.f) * dinv[i2];
            s3 += fmaxf(Hs[(size_t)i3 * 64 + lane] * sc + sh, 0.f) * dinv[i3];
        }
        for (; j < e; ++j) {
            int i0 = col[j];
            s0 += fmaxf(Hs[(size_t)i0 * 64 + lane] * sc + sh, 0.f) * dinv[i0];
        }
        out[(size_t)node * 64 + lane] = dinv[node] * ((s0 + s1) + (s2 + s3));
    } else {
        float s0 = Hs[(size_t)node * 64 + lane];
        float s1 = 0.f, s2 = 0.f, s3 = 0.f;
        int j = b;
        for (; j + 4 <= e; j += 4) {
            int i0 = col[j], i1 = col[j + 1], i2 = col[j + 2], i3 = col[j + 3];
            s0 += Hs[(size_t)i0 * 64 + lane];
            s1 += Hs[(size_t)i1 * 64 + lane];
            s2 += Hs[(size_t)i2 * 64 + lane];
            s3 += Hs[(size_t)i3 * 64 + lane];
        }
        for (; j < e; ++j) s0 += Hs[(size_t)col[j] * 64 + lane];
        out[(size_t)node * 64 + lane] = dinv[node] * ((s0 + s1) + (s2 + s3));
    }
}

// ---------------- BN statistics ----------------

__global__ __launch_bounds__(256) void k_bnstat1(const float* __restrict__ X,
                                                 float* __restrict__ part, int n, int W) {
    int cols4 = W >> 2;
    int c4 = threadIdx.x & (cols4 - 1);
    int rsub = threadIdx.x / cols4;
    int lanes = 256 / cols4;
    int nrg = (n + lanes - 1) / lanes;
    float4 s = make_float4(0.f, 0.f, 0.f, 0.f);
    float4 s2 = make_float4(0.f, 0.f, 0.f, 0.f);
    for (int rg = blockIdx.x; rg < nrg; rg += gridDim.x) {
        int r = rg * lanes + rsub;
        if (r < n) {
            float4 v = *(const float4*)(X + (size_t)r * W + (c4 << 2));
            s.x += v.x; s.y += v.y; s.z += v.z; s.w += v.w;
            s2.x += v.x * v.x; s2.y += v.y * v.y; s2.z += v.z * v.z; s2.w += v.w * v.w;
        }
    }
    __shared__ float4 ls[256], ls2[256];
    ls[threadIdx.x] = s;
    ls2[threadIdx.x] = s2;
    __syncthreads();
    for (int off = lanes >> 1; off > 0; off >>= 1) {
        if (rsub < off) {
            int i = threadIdx.x, j = threadIdx.x + off * cols4;
            float4 a = ls[i], b = ls[j];
            a.x += b.x; a.y += b.y; a.z += b.z; a.w += b.w;
            ls[i] = a;
            float4 a2 = ls2[i], b2 = ls2[j];
            a2.x += b2.x; a2.y += b2.y; a2.z += b2.z; a2.w += b2.w;
            ls2[i] = a2;
        }
        __syncthreads();
    }
    if (rsub == 0) {
        *(float4*)(part + (size_t)blockIdx.x * W + (c4 << 2)) = ls[c4];
        *(float4*)(part + (size_t)(gridDim.x + blockIdx.x) * W + (c4 << 2)) = ls2[c4];
    }
}

__global__ __launch_bounds__(1024) void k_bnstat2(const float* __restrict__ part,
                                                  const float* __restrict__ g,
                                                  const float* __restrict__ be,
                                                  float* __restrict__ scale,
                                                  float* __restrict__ shift,
                                                  int nblk, int W, float inv_n) {
    int t = threadIdx.x;
    int c = t & (W - 1);
    int q = t / W;
    int nq = 1024 / W;
    int per = nblk / nq;
    float s = 0.f, s2 = 0.f;
    for (int b = q * per; b < (q + 1) * per; ++b) {
        s  += part[(size_t)b * W + c];
        s2 += part[(size_t)(nblk + b) * W + c];
    }
    __shared__ float ls[1024], ls2[1024];
    ls[t] = s;
    ls2[t] = s2;
    __syncthreads();
    if (q == 0) {
        for (int k = 1; k < nq; ++k) {
            s += ls[k * W + c];
            s2 += ls2[k * W + c];
        }
        float m = s * inv_n;
        float v = s2 * inv_n - m * m;
        float sc = g[c] * rsqrtf(v + BN_EPS);
        scale[c] = sc;
        shift[c] = be[c] - m * sc;
    }
}

// ---------------- final: out = relu(out*scale[c] + shift[c] + x) (in place, W=256) ----------------

__global__ void k_final(float* __restrict__ out, const float* __restrict__ x,
                        const float* __restrict__ scale, const float* __restrict__ shift, int n) {
    int idx = blockIdx.x * blockDim.x + threadIdx.x;
    int total = n * 64;
    for (int i = idx; i < total; i += gridDim.x * blockDim.x) {
        float4 v = *(const float4*)(out + (size_t)i * 4);
        float4 xv = *(const float4*)(x + (size_t)i * 4);
        int c4 = (i & 63) << 2;
        float4 sc = *(const float4*)(scale + c4);
        float4 sh = *(const float4*)(shift + c4);
        v.x = fmaxf(v.x * sc.x + sh.x + xv.x, 0.f);
        v.y = fmaxf(v.y * sc.y + sh.y + xv.y, 0.f);
        v.z = fmaxf(v.z * sc.z + sh.z + xv.z, 0.f);
        v.w = fmaxf(v.w * sc.w + sh.w + xv.w, 0.f);
        *(float4*)(out + (size_t)i * 4) = v;
    }
}

// ---------------- launch ----------------

extern "C" void kernel_launch(void* const* d_in, const int* in_sizes, int n_in,
                              void* d_out, int out_size, void* d_ws, size_t ws_size,
                              hipStream_t stream) {
    const float* x   = (const float*)d_in[0];
    const int*   ei  = (const int*)d_in[1];
    const int    N   = in_sizes[2];
    const int    E   = in_sizes[1] / 2;
    const float* W1  = (const float*)d_in[3];
    const float* g1  = (const float*)d_in[5];
    const float* be1 = (const float*)d_in[6];
    const float* W2  = (const float*)d_in[7];
    const float* g2  = (const float*)d_in[9];
    const float* be2 = (const float*)d_in[10];
    const float* W3  = (const float*)d_in[11];
    const float* g3  = (const float*)d_in[13];
    const float* be3 = (const float*)d_in[14];
    float* out = (float*)d_out;

    char* p = (char*)d_ws;
    auto alloc = [&](size_t bytes) {
        char* q = p;
        p += (bytes + 255) & ~(size_t)255;
        return q;
    };
    int*   cnt    = (int*)alloc((size_t)N * 4);
    int*   rowptr = (int*)alloc((size_t)(N + 1) * 4);
    int*   pos    = (int*)alloc((size_t)N * 4);
    int*   colv   = (int*)alloc((size_t)E * 4);
    float* dinv   = (float*)alloc((size_t)N * 4);
    int*   bsum   = (int*)alloc(256 * 4);
    int*   boff   = (int*)alloc(256 * 4);
    float* bufA   = (float*)alloc((size_t)N * 64 * 4);
    float* bufB   = (float*)alloc((size_t)N * 64 * 4);
    float* part   = (float*)alloc((size_t)2 * NBLK_STAT * 256 * 4);
    float* scale  = (float*)alloc(256 * 4);
    float* shift  = (float*)alloc(256 * 4);

    const int* srcp = ei;
    const int* dstp = ei + E;

    hipMemsetAsync(cnt, 0, (size_t)N * 4, stream);
    int eb = (E + 255) / 256;
    int nscan = (N + 255) / 256;
    k_degree<<<eb, 256, 0, stream>>>(dstp, cnt, E);
    k_scan1<<<nscan, 256, 0, stream>>>(cnt, bsum, N);
    k_scan2<<<1, 256, 0, stream>>>(bsum, boff, nscan);
    k_scan3<<<nscan, 256, 0, stream>>>(cnt, boff, rowptr, pos, dinv, N, E);
    k_fill<<<eb, 256, 0, stream>>>(srcp, dstp, pos, colv, E);

    dim3 gemm_g((N + 63) / 64, 1);
    dim3 gemm3_g((N + 63) / 64, 4);
    int aggb = (N * 64 + 255) / 256;

    // conv1: Hs1 = (x @ W1) * dinv   -> agg -> bufB (pre-BN)
    k_gemm<<<gemm_g, 256, 0, stream>>>(x, W1, bufA, nullptr, nullptr, dinv, N, 256, 64);
    k_agg64<<<aggb, 256, 0, stream>>>(bufA, dinv, rowptr, colv, bufB, N, nullptr, nullptr);
    k_bnstat1<<<NBLK_STAT, 256, 0, stream>>>(bufB, part, N, 64);
    k_bnstat2<<<1, 1024, 0, stream>>>(part, g1, be1, scale, shift, NBLK_STAT, 64, 1.0f / N);

    // conv2: BN1+ReLU fused into GEMM A-load; epilogue ×dinv; agg -> bufB (pre-BN)
    k_gemm<<<gemm_g, 256, 0, stream>>>(bufB, W2, bufA, scale, shift, dinv, N, 64, 64);
    k_agg64<<<aggb, 256, 0, stream>>>(bufA, dinv, rowptr, colv, bufB, N, nullptr, nullptr);
    k_bnstat1<<<NBLK_STAT, 256, 0, stream>>>(bufB, part, N, 64);
    k_bnstat2<<<1, 1024, 0, stream>>>(part, g2, be2, scale, shift, NBLK_STAT, 64, 1.0f / N);

    // conv3 (agg-first, BN2+ReLU+dinv fused into gather): bufB -> bufA; out = bufA @ W3
    k_agg64<<<aggb, 256, 0, stream>>>(bufB, dinv, rowptr, colv, bufA, N, scale, shift);
    k_gemm<<<gemm3_g, 256, 0, stream>>>(bufA, W3, out, nullptr, nullptr, nullptr, N, 64, 256);
    k_bnstat1<<<NBLK_STAT, 256, 0, stream>>>(out, part, N, 256);
    k_bnstat2<<<1, 1024, 0, stream>>>(part, g3, be3, scale, shift, NBLK_STAT, 256, 1.0f / N);

    k_final<<<2048, 256, 0, stream>>>(out, x, scale, shift, N);
}

// Round 5
// 422.223 us; speedup vs baseline: 2.0652x; 1.0898x over previous
//
#include <hip/hip_runtime.h>
#include <hip/hip_bf16.h>

#define BN_EPS 1e-5f
#define NBLK_STAT 256
#define BK 16

// ---------------- degree / CSR build ----------------

__global__ void k_degree(const int* __restrict__ dst, int* __restrict__ cnt, int E) {
    int e = blockIdx.x * blockDim.x + threadIdx.x;
    if (e < E) atomicAdd(&cnt[dst[e]], 1);
}

__global__ __launch_bounds__(256) void k_scan1(const int* __restrict__ cnt,
                                               int* __restrict__ bsum, int n) {
    __shared__ int l[256];
    int i = blockIdx.x * 256 + threadIdx.x;
    l[threadIdx.x] = (i < n) ? cnt[i] : 0;
    __syncthreads();
    for (int off = 128; off > 0; off >>= 1) {
        if (threadIdx.x < off) l[threadIdx.x] += l[threadIdx.x + off];
        __syncthreads();
    }
    if (threadIdx.x == 0) bsum[blockIdx.x] = l[0];
}

__global__ __launch_bounds__(256) void k_scan2(const int* __restrict__ bsum,
                                               int* __restrict__ boff, int nblk) {
    __shared__ int l[256];
    int t = threadIdx.x;
    l[t] = (t < nblk) ? bsum[t] : 0;
    __syncthreads();
    for (int off = 1; off < 256; off <<= 1) {
        int v = l[t];
        int add = (t >= off) ? l[t - off] : 0;
        __syncthreads();
        l[t] = v + add;
        __syncthreads();
    }
    boff[t] = (t == 0) ? 0 : l[t - 1];  // exclusive
}

__global__ __launch_bounds__(256) void k_scan3(const int* __restrict__ cnt,
                                               const int* __restrict__ boff,
                                               int* __restrict__ rowptr,
                                               int* __restrict__ pos,
                                               float* __restrict__ dinv, int n, int E) {
    __shared__ int l[256];
    int t = threadIdx.x;
    int i = blockIdx.x * 256 + t;
    int c = (i < n) ? cnt[i] : 0;
    l[t] = c;
    __syncthreads();
    for (int off = 1; off < 256; off <<= 1) {
        int v = l[t];
        int add = (t >= off) ? l[t - off] : 0;
        __syncthreads();
        l[t] = v + add;
        __syncthreads();
    }
    if (i < n) {
        int excl = boff[blockIdx.x] + l[t] - c;
        rowptr[i] = excl;
        pos[i] = excl;
        dinv[i] = rsqrtf((float)c + 1.0f);
    }
    if (blockIdx.x == 0 && t == 0) rowptr[n] = E;
}

__global__ void k_fill(const int* __restrict__ src, const int* __restrict__ dst,
                       int* __restrict__ pos, int* __restrict__ col, int E) {
    int e = blockIdx.x * blockDim.x + threadIdx.x;
    if (e < E) {
        int d = dst[e];
        int p = atomicAdd(&pos[d], 1);
        col[p] = src[e];
    }
}

// ---------------- GEMM: C[n,OUT] = transform(A[n,K]) @ W[K,OUT] ----------------
// 128 rows x 64 cols per block, 128 threads (2 waves), 8x8 acc per thread.
// A stored k-major (transposed) in LDS so 8 rows are contiguous; BK=16,
// double-buffered with register prefetch, one barrier per k-tile.
// transform (scale != null): a = relu(a*scale[k] + shift[k]); epilogue ×dinv[row].

__global__ __launch_bounds__(128) void k_gemm(const float* __restrict__ A,
                                              const float* __restrict__ W,
                                              float* __restrict__ C,
                                              const float* __restrict__ scale,
                                              const float* __restrict__ shift,
                                              const float* __restrict__ dinv,
                                              int n, int K, int OUT) {
    __shared__ float At[2][BK][128];   // [k][row]
    __shared__ float Ws[2][BK][64];    // [k][col]
    const int row0 = blockIdx.x * 128;
    const int col0 = blockIdx.y * 64;
    const int tid = threadIdx.x;
    const int tr = tid >> 3;           // 0..15 -> rows 8*tr..8*tr+7
    const int tc = tid & 7;            // 0..7  -> cols 8*tc..8*tc+7
    const int wr = tid >> 4;           // W stage: k rows wr, wr+8
    const int wc = (tid & 15) << 2;    // W stage: col quad
    const int NT = K / BK;

    float4 pa[4], pw[2];
    float acc[8][8] = {};

#define PREFETCH(k0)                                                                \
    {                                                                               \
        int gr = row0 + tid;                                                        \
        if (gr < n) {                                                               \
            const float* ap = A + (size_t)gr * K + (k0);                            \
            pa[0] = *(const float4*)(ap + 0);                                       \
            pa[1] = *(const float4*)(ap + 4);                                       \
            pa[2] = *(const float4*)(ap + 8);                                       \
            pa[3] = *(const float4*)(ap + 12);                                      \
        } else {                                                                    \
            pa[0] = pa[1] = pa[2] = pa[3] = make_float4(0.f, 0.f, 0.f, 0.f);        \
        }                                                                           \
        if (scale) {                                                                \
            _Pragma("unroll")                                                       \
            for (int j = 0; j < 4; ++j) {                                           \
                float4 sc = *(const float4*)(scale + (k0) + 4 * j);                 \
                float4 sh = *(const float4*)(shift + (k0) + 4 * j);                 \
                pa[j].x = fmaxf(pa[j].x * sc.x + sh.x, 0.f);                        \
                pa[j].y = fmaxf(pa[j].y * sc.y + sh.y, 0.f);                        \
                pa[j].z = fmaxf(pa[j].z * sc.z + sh.z, 0.f);                        \
                pa[j].w = fmaxf(pa[j].w * sc.w + sh.w, 0.f);                        \
            }                                                                       \
        }                                                                           \
        pw[0] = *(const float4*)(W + (size_t)((k0) + wr) * OUT + col0 + wc);        \
        pw[1] = *(const float4*)(W + (size_t)((k0) + wr + 8) * OUT + col0 + wc);    \
    }

#define STORE(b)                                                                    \
    {                                                                               \
        _Pragma("unroll")                                                           \
        for (int j = 0; j < 4; ++j) {                                               \
            At[b][4 * j + 0][tid] = pa[j].x;                                        \
            At[b][4 * j + 1][tid] = pa[j].y;                                        \
            At[b][4 * j + 2][tid] = pa[j].z;                                        \
            At[b][4 * j + 3][tid] = pa[j].w;                                        \
        }                                                                           \
        *(float4*)&Ws[b][wr][wc] = pw[0];                                           \
        *(float4*)&Ws[b][wr + 8][wc] = pw[1];                                       \
    }

    PREFETCH(0)
    STORE(0)
    __syncthreads();

    for (int t = 0; t < NT; ++t) {
        int buf = t & 1;
        if (t + 1 < NT) PREFETCH((t + 1) * BK)
        #pragma unroll
        for (int kk = 0; kk < BK; ++kk) {
            float4 a0 = *(const float4*)&At[buf][kk][tr << 3];
            float4 a1 = *(const float4*)&At[buf][kk][(tr << 3) + 4];
            float4 w0 = *(const float4*)&Ws[buf][kk][tc << 3];
            float4 w1 = *(const float4*)&Ws[buf][kk][(tc << 3) + 4];
            float av[8] = {a0.x, a0.y, a0.z, a0.w, a1.x, a1.y, a1.z, a1.w};
            float wv[8] = {w0.x, w0.y, w0.z, w0.w, w1.x, w1.y, w1.z, w1.w};
            #pragma unroll
            for (int i = 0; i < 8; ++i)
                #pragma unroll
                for (int u = 0; u < 8; ++u)
                    acc[i][u] += av[i] * wv[u];
        }
        if (t + 1 < NT) {
            STORE(buf ^ 1)
            __syncthreads();
        }
    }
#undef PREFETCH
#undef STORE

    #pragma unroll
    for (int i = 0; i < 8; ++i) {
        int gr = row0 + (tr << 3) + i;
        if (gr >= n) continue;
        float dv = dinv ? dinv[gr] : 1.0f;
        float* cp = C + (size_t)gr * OUT + col0 + (tc << 3);
        float4 o0 = make_float4(acc[i][0] * dv, acc[i][1] * dv, acc[i][2] * dv, acc[i][3] * dv);
        float4 o1 = make_float4(acc[i][4] * dv, acc[i][5] * dv, acc[i][6] * dv, acc[i][7] * dv);
        *(float4*)cp = o0;
        *(float4*)(cp + 4) = o1;
    }
}

// ---------------- aggregation (width 64): 4 nodes per wave, 16 lanes × float4 each ----------------
// plain (scale==null):  out[i] = dinv[i] * (Hs[i] + sum_{src} Hs[src])        (Hs already ×dinv)
// fused (scale!=null):  T(v,j) = relu(v*scale[c]+shift[c]) * dinv[j]
//                       out[i] = dinv[i] * (T(Hs[i],i) + sum_{src} T(Hs[src],src))

__global__ void k_agg64(const float4* __restrict__ Hs4, const float* __restrict__ dinv,
                        const int* __restrict__ rowptr, const int* __restrict__ col,
                        float4* __restrict__ out4, int n,
                        const float* __restrict__ scale, const float* __restrict__ shift) {
    int wave = (blockIdx.x * blockDim.x + threadIdx.x) >> 6;
    int lane = threadIdx.x & 63;
    int cq = lane & 15;                 // channel quad: cols 4cq..4cq+3
    int node = wave * 4 + (lane >> 4);  // 4 nodes per wave
    bool valid = node < n;
    int b = 0, deg = 0;
    if (valid) {
        b = rowptr[node];
        deg = rowptr[node + 1] - b;
    }
    int m = deg;
    m = max(m, __shfl_xor(m, 16));
    m = max(m, __shfl_xor(m, 32));      // max degree over the wave's 4 nodes

    float4 a0 = make_float4(0.f, 0.f, 0.f, 0.f), a1 = a0, a2 = a0, a3 = a0;

    if (scale) {
        float4 sc = *(const float4*)(scale + (cq << 2));
        float4 sh = *(const float4*)(shift + (cq << 2));
        if (valid) {
            float4 v = Hs4[(size_t)node * 16 + cq];
            float dv = dinv[node];
            a0.x = fmaxf(v.x * sc.x + sh.x, 0.f) * dv;
            a0.y = fmaxf(v.y * sc.y + sh.y, 0.f) * dv;
            a0.z = fmaxf(v.z * sc.z + sh.z, 0.f) * dv;
            a0.w = fmaxf(v.w * sc.w + sh.w, 0.f) * dv;
        }
        for (int j = 0; j < m; j += 4) {
            if (j < deg) {
                int idx = col[b + j];
                float4 v = Hs4[(size_t)idx * 16 + cq];
                float dv = dinv[idx];
                a0.x += fmaxf(v.x * sc.x + sh.x, 0.f) * dv;
                a0.y += fmaxf(v.y * sc.y + sh.y, 0.f) * dv;
                a0.z += fmaxf(v.z * sc.z + sh.z, 0.f) * dv;
                a0.w += fmaxf(v.w * sc.w + sh.w, 0.f) * dv;
            }
            if (j + 1 < deg) {
                int idx = col[b + j + 1];
                float4 v = Hs4[(size_t)idx * 16 + cq];
                float dv = dinv[idx];
                a1.x += fmaxf(v.x * sc.x + sh.x, 0.f) * dv;
                a1.y += fmaxf(v.y * sc.y + sh.y, 0.f) * dv;
                a1.z += fmaxf(v.z * sc.z + sh.z, 0.f) * dv;
                a1.w += fmaxf(v.w * sc.w + sh.w, 0.f) * dv;
            }
            if (j + 2 < deg) {
                int idx = col[b + j + 2];
                float4 v = Hs4[(size_t)idx * 16 + cq];
                float dv = dinv[idx];
                a2.x += fmaxf(v.x * sc.x + sh.x, 0.f) * dv;
                a2.y += fmaxf(v.y * sc.y + sh.y, 0.f) * dv;
                a2.z += fmaxf(v.z * sc.z + sh.z, 0.f) * dv;
                a2.w += fmaxf(v.w * sc.w + sh.w, 0.f) * dv;
            }
            if (j + 3 < deg) {
                int idx = col[b + j + 3];
                float4 v = Hs4[(size_t)idx * 16 + cq];
                float dv = dinv[idx];
                a3.x += fmaxf(v.x * sc.x + sh.x, 0.f) * dv;
                a3.y += fmaxf(v.y * sc.y + sh.y, 0.f) * dv;
                a3.z += fmaxf(v.z * sc.z + sh.z, 0.f) * dv;
                a3.w += fmaxf(v.w * sc.w + sh.w, 0.f) * dv;
            }
        }
    } else {
        if (valid) a0 = Hs4[(size_t)node * 16 + cq];
        for (int j = 0; j < m; j += 4) {
            if (j < deg) {
                float4 v = Hs4[(size_t)col[b + j] * 16 + cq];
                a0.x += v.x; a0.y += v.y; a0.z += v.z; a0.w += v.w;
            }
            if (j + 1 < deg) {
                float4 v = Hs4[(size_t)col[b + j + 1] * 16 + cq];
                a1.x += v.x; a1.y += v.y; a1.z += v.z; a1.w += v.w;
            }
            if (j + 2 < deg) {
                float4 v = Hs4[(size_t)col[b + j + 2] * 16 + cq];
                a2.x += v.x; a2.y += v.y; a2.z += v.z; a2.w += v.w;
            }
            if (j + 3 < deg) {
                float4 v = Hs4[(size_t)col[b + j + 3] * 16 + cq];
                a3.x += v.x; a3.y += v.y; a3.z += v.z; a3.w += v.w;
            }
        }
    }
    if (valid) {
        float dn = dinv[node];
        float4 o;
        o.x = dn * ((a0.x + a1.x) + (a2.x + a3.x));
        o.y = dn * ((a0.y + a1.y) + (a2.y + a3.y));
        o.z = dn * ((a0.z + a1.z) + (a2.z + a3.z));
        o.w = dn * ((a0.w + a1.w) + (a2.w + a3.w));
        out4[(size_t)node * 16 + cq] = o;
    }
}

// ---------------- BN statistics ----------------

__global__ __launch_bounds__(256) void k_bnstat1(const float* __restrict__ X,
                                                 float* __restrict__ part, int n, int W) {
    int cols4 = W >> 2;
    int c4 = threadIdx.x & (cols4 - 1);
    int rsub = threadIdx.x / cols4;
    int lanes = 256 / cols4;
    int nrg = (n + lanes - 1) / lanes;
    float4 s = make_float4(0.f, 0.f, 0.f, 0.f);
    float4 s2 = make_float4(0.f, 0.f, 0.f, 0.f);
    for (int rg = blockIdx.x; rg < nrg; rg += gridDim.x) {
        int r = rg * lanes + rsub;
        if (r < n) {
            float4 v = *(const float4*)(X + (size_t)r * W + (c4 << 2));
            s.x += v.x; s.y += v.y; s.z += v.z; s.w += v.w;
            s2.x += v.x * v.x; s2.y += v.y * v.y; s2.z += v.z * v.z; s2.w += v.w * v.w;
        }
    }
    __shared__ float4 ls[256], ls2[256];
    ls[threadIdx.x] = s;
    ls2[threadIdx.x] = s2;
    __syncthreads();
    for (int off = lanes >> 1; off > 0; off >>= 1) {
        if (rsub < off) {
            int i = threadIdx.x, j = threadIdx.x + off * cols4;
            float4 a = ls[i], b = ls[j];
            a.x += b.x; a.y += b.y; a.z += b.z; a.w += b.w;
            ls[i] = a;
            float4 a2 = ls2[i], b2 = ls2[j];
            a2.x += b2.x; a2.y += b2.y; a2.z += b2.z; a2.w += b2.w;
            ls2[i] = a2;
        }
        __syncthreads();
    }
    if (rsub == 0) {
        *(float4*)(part + (size_t)blockIdx.x * W + (c4 << 2)) = ls[c4];
        *(float4*)(part + (size_t)(gridDim.x + blockIdx.x) * W + (c4 << 2)) = ls2[c4];
    }
}

__global__ __launch_bounds__(1024) void k_bnstat2(const float* __restrict__ part,
                                                  const float* __restrict__ g,
                                                  const float* __restrict__ be,
                                                  float* __restrict__ scale,
                                                  float* __restrict__ shift,
                                                  int nblk, int W, float inv_n) {
    int t = threadIdx.x;
    int c = t & (W - 1);
    int q = t / W;
    int nq = 1024 / W;
    int per = nblk / nq;
    float s = 0.f, s2 = 0.f;
    for (int b = q * per; b < (q + 1) * per; ++b) {
        s  += part[(size_t)b * W + c];
        s2 += part[(size_t)(nblk + b) * W + c];
    }
    __shared__ float ls[1024], ls2[1024];
    ls[t] = s;
    ls2[t] = s2;
    __syncthreads();
    if (q == 0) {
        for (int k = 1; k < nq; ++k) {
            s += ls[k * W + c];
            s2 += ls2[k * W + c];
        }
        float m = s * inv_n;
        float v = s2 * inv_n - m * m;
        float sc = g[c] * rsqrtf(v + BN_EPS);
        scale[c] = sc;
        shift[c] = be[c] - m * sc;
    }
}

// ---------------- final: out = relu(out*scale[c] + shift[c] + x) (in place, W=256) ----------------

__global__ void k_final(float* __restrict__ out, const float* __restrict__ x,
                        const float* __restrict__ scale, const float* __restrict__ shift, int n) {
    int idx = blockIdx.x * blockDim.x + threadIdx.x;
    int total = n * 64;
    for (int i = idx; i < total; i += gridDim.x * blockDim.x) {
        float4 v = *(const float4*)(out + (size_t)i * 4);
        float4 xv = *(const float4*)(x + (size_t)i * 4);
        int c4 = (i & 63) << 2;
        float4 sc = *(const float4*)(scale + c4);
        float4 sh = *(const float4*)(shift + c4);
        v.x = fmaxf(v.x * sc.x + sh.x + xv.x, 0.f);
        v.y = fmaxf(v.y * sc.y + sh.y + xv.y, 0.f);
        v.z = fmaxf(v.z * sc.z + sh.z + xv.z, 0.f);
        v.w = fmaxf(v.w * sc.w + sh.w + xv.w, 0.f);
        *(float4*)(out + (size_t)i * 4) = v;
    }
}

// ---------------- launch ----------------

extern "C" void kernel_launch(void* const* d_in, const int* in_sizes, int n_in,
                              void* d_out, int out_size, void* d_ws, size_t ws_size,
                              hipStream_t stream) {
    const float* x   = (const float*)d_in[0];
    const int*   ei  = (const int*)d_in[1];
    const int    N   = in_sizes[2];
    const int    E   = in_sizes[1] / 2;
    const float* W1  = (const float*)d_in[3];
    const float* g1  = (const float*)d_in[5];
    const float* be1 = (const float*)d_in[6];
    const float* W2  = (const float*)d_in[7];
    const float* g2  = (const float*)d_in[9];
    const float* be2 = (const float*)d_in[10];
    const float* W3  = (const float*)d_in[11];
    const float* g3  = (const float*)d_in[13];
    const float* be3 = (const float*)d_in[14];
    float* out = (float*)d_out;

    char* p = (char*)d_ws;
    auto alloc = [&](size_t bytes) {
        char* q = p;
        p += (bytes + 255) & ~(size_t)255;
        return q;
    };
    int*   cnt    = (int*)alloc((size_t)N * 4);
    int*   rowptr = (int*)alloc((size_t)(N + 1) * 4);
    int*   pos    = (int*)alloc((size_t)N * 4);
    int*   colv   = (int*)alloc((size_t)E * 4);
    float* dinv   = (float*)alloc((size_t)N * 4);
    int*   bsum   = (int*)alloc(256 * 4);
    int*   boff   = (int*)alloc(256 * 4);
    float* bufA   = (float*)alloc((size_t)N * 64 * 4);
    float* bufB   = (float*)alloc((size_t)N * 64 * 4);
    float* part   = (float*)alloc((size_t)2 * NBLK_STAT * 256 * 4);
    float* scale  = (float*)alloc(256 * 4);
    float* shift  = (float*)alloc(256 * 4);

    const int* srcp = ei;
    const int* dstp = ei + E;

    hipMemsetAsync(cnt, 0, (size_t)N * 4, stream);
    int eb = (E + 255) / 256;
    int nscan = (N + 255) / 256;
    k_degree<<<eb, 256, 0, stream>>>(dstp, cnt, E);
    k_scan1<<<nscan, 256, 0, stream>>>(cnt, bsum, N);
    k_scan2<<<1, 256, 0, stream>>>(bsum, boff, nscan);
    k_scan3<<<nscan, 256, 0, stream>>>(cnt, boff, rowptr, pos, dinv, N, E);
    k_fill<<<eb, 256, 0, stream>>>(srcp, dstp, pos, colv, E);

    dim3 gemm_g((N + 127) / 128, 1);
    dim3 gemm3_g((N + 127) / 128, 4);
    int aggb = ((N + 3) / 4 * 64 + 255) / 256;   // 4 nodes per wave

    // conv1: Hs1 = (x @ W1) * dinv   -> agg -> bufB (pre-BN)
    k_gemm<<<gemm_g, 128, 0, stream>>>(x, W1, bufA, nullptr, nullptr, dinv, N, 256, 64);
    k_agg64<<<aggb, 256, 0, stream>>>((const float4*)bufA, dinv, rowptr, colv, (float4*)bufB, N, nullptr, nullptr);
    k_bnstat1<<<NBLK_STAT, 256, 0, stream>>>(bufB, part, N, 64);
    k_bnstat2<<<1, 1024, 0, stream>>>(part, g1, be1, scale, shift, NBLK_STAT, 64, 1.0f / N);

    // conv2: BN1+ReLU fused into GEMM A-load; epilogue ×dinv; agg -> bufB (pre-BN)
    k_gemm<<<gemm_g, 128, 0, stream>>>(bufB, W2, bufA, scale, shift, dinv, N, 64, 64);
    k_agg64<<<aggb, 256, 0, stream>>>((const float4*)bufA, dinv, rowptr, colv, (float4*)bufB, N, nullptr, nullptr);
    k_bnstat1<<<NBLK_STAT, 256, 0, stream>>>(bufB, part, N, 64);
    k_bnstat2<<<1, 1024, 0, stream>>>(part, g2, be2, scale, shift, NBLK_STAT, 64, 1.0f / N);

    // conv3 (agg-first, BN2+ReLU+dinv fused into gather): bufB -> bufA; out = bufA @ W3
    k_agg64<<<aggb, 256, 0, stream>>>((const float4*)bufB, dinv, rowptr, colv, (float4*)bufA, N, scale, shift);
    k_gemm<<<gemm3_g, 128, 0, stream>>>(bufA, W3, out, nullptr, nullptr, nullptr, N, 64, 256);
    k_bnstat1<<<NBLK_STAT, 256, 0, stream>>>(out, part, N, 256);
    k_bnstat2<<<1, 1024, 0, stream>>>(part, g3, be3, scale, shift, NBLK_STAT, 256, 1.0f / N);

    k_final<<<2048, 256, 0, stream>>>(out, x, scale, shift, N);
}

// Round 6
// 314.184 us; speedup vs baseline: 2.7754x; 1.3439x over previous
//
#include <hip/hip_runtime.h>
#include <hip/hip_bf16.h>

#define BN_EPS 1e-5f
#define NBLK_STAT 256

typedef __attribute__((ext_vector_type(8))) short short8;
typedef __attribute__((ext_vector_type(4))) float f32x4;

__device__ __forceinline__ ushort f2bf(float x) {
    uint u = __float_as_uint(x);
    u += 0x7FFF + ((u >> 16) & 1);      // round-to-nearest-even
    return (ushort)(u >> 16);
}
__device__ __forceinline__ float bf2f(uint h) { return __uint_as_float(h << 16); }

// ---------------- degree / CSR build ----------------

__global__ void k_degree(const int* __restrict__ dst, int* __restrict__ cnt, int E) {
    int e = blockIdx.x * blockDim.x + threadIdx.x;
    if (e < E) atomicAdd(&cnt[dst[e]], 1);
}

__global__ __launch_bounds__(256) void k_scan1(const int* __restrict__ cnt,
                                               int* __restrict__ bsum, int n) {
    __shared__ int l[256];
    int i = blockIdx.x * 256 + threadIdx.x;
    l[threadIdx.x] = (i < n) ? cnt[i] : 0;
    __syncthreads();
    for (int off = 128; off > 0; off >>= 1) {
        if (threadIdx.x < off) l[threadIdx.x] += l[threadIdx.x + off];
        __syncthreads();
    }
    if (threadIdx.x == 0) bsum[blockIdx.x] = l[0];
}

__global__ __launch_bounds__(256) void k_scan2(const int* __restrict__ bsum,
                                               int* __restrict__ boff, int nblk) {
    __shared__ int l[256];
    int t = threadIdx.x;
    l[t] = (t < nblk) ? bsum[t] : 0;
    __syncthreads();
    for (int off = 1; off < 256; off <<= 1) {
        int v = l[t];
        int add = (t >= off) ? l[t - off] : 0;
        __syncthreads();
        l[t] = v + add;
        __syncthreads();
    }
    boff[t] = (t == 0) ? 0 : l[t - 1];  // exclusive
}

__global__ __launch_bounds__(256) void k_scan3(const int* __restrict__ cnt,
                                               const int* __restrict__ boff,
                                               int* __restrict__ rowptr,
                                               int* __restrict__ pos,
                                               float* __restrict__ dinv, int n, int E) {
    __shared__ int l[256];
    int t = threadIdx.x;
    int i = blockIdx.x * 256 + t;
    int c = (i < n) ? cnt[i] : 0;
    l[t] = c;
    __syncthreads();
    for (int off = 1; off < 256; off <<= 1) {
        int v = l[t];
        int add = (t >= off) ? l[t - off] : 0;
        __syncthreads();
        l[t] = v + add;
        __syncthreads();
    }
    if (i < n) {
        int excl = boff[blockIdx.x] + l[t] - c;
        rowptr[i] = excl;
        pos[i] = excl;
        dinv[i] = rsqrtf((float)c + 1.0f);
    }
    if (blockIdx.x == 0 && t == 0) rowptr[n] = E;
}

__global__ void k_fill(const int* __restrict__ src, const int* __restrict__ dst,
                       int* __restrict__ pos, int* __restrict__ col, int E) {
    int e = blockIdx.x * blockDim.x + threadIdx.x;
    if (e < E) {
        int d = dst[e];
        int p = atomicAdd(&pos[d], 1);
        col[p] = src[e];
    }
}

// ---------------- MFMA bf16 GEMM: C[n,OUT] = transform(A[n,K]) @ W[K,OUT] ----------------
// A from f32 (Af) or bf16 (Ab). transform (scale!=null): a = relu(a*scale[k]+shift[k]).
// Output bf16 (Cb) or f32 (Cf); epilogue ×dinv[row] if dinv != null.
// Block: 64M × 64N, 256 thr = 4 waves; wave w owns rows 16w..16w+15, all 64 cols.
// Per 32-k step: stage A[64][32] and W^T[64][32] as bf16 in LDS (stride 40: bank-safe).

__global__ __launch_bounds__(256) void k_gemm_mfma(
    const float* __restrict__ Af, const ushort* __restrict__ Ab,
    const float* __restrict__ Wg,
    ushort* __restrict__ Cb, float* __restrict__ Cf,
    const float* __restrict__ scale, const float* __restrict__ shift,
    const float* __restrict__ dinv,
    int n, int K, int OUT)
{
    __shared__ ushort As[64][40];   // [row][k]
    __shared__ ushort Wt[64][40];   // [col][k]
    const int row0 = blockIdx.x * 64;
    const int col0 = blockIdx.y * 64;
    const int tid = threadIdx.x;
    const int wv = tid >> 6;
    const int lane = tid & 63;
    const int fr = lane & 15;        // MFMA row/col within frag
    const int kb = lane >> 4;        // MFMA k-block (0..3)

    const int ar  = tid >> 2;         // A stage: row 0..63
    const int akc = (tid & 3) << 3;   // A stage: k offset 0,8,16,24
    const int wk  = tid >> 3;         // W stage: k row 0..31
    const int wcg = (tid & 7) << 3;   // W stage: col offset 0..56

    f32x4 acc[4];
    acc[0] = acc[1] = acc[2] = acc[3] = (f32x4){0.f, 0.f, 0.f, 0.f};

    for (int k0 = 0; k0 < K; k0 += 32) {
        // ---- stage A (f32 or bf16 -> transform -> bf16 LDS) ----
        float v[8];
        int gr = row0 + ar;
        if (gr < n) {
            if (Af) {
                const float* ap = Af + (size_t)gr * K + k0 + akc;
                float4 x0 = *(const float4*)ap;
                float4 x1 = *(const float4*)(ap + 4);
                v[0] = x0.x; v[1] = x0.y; v[2] = x0.z; v[3] = x0.w;
                v[4] = x1.x; v[5] = x1.y; v[6] = x1.z; v[7] = x1.w;
            } else {
                uint4 u = *(const uint4*)(Ab + (size_t)gr * K + k0 + akc);
                v[0] = bf2f(u.x & 0xffffu); v[1] = bf2f(u.x >> 16);
                v[2] = bf2f(u.y & 0xffffu); v[3] = bf2f(u.y >> 16);
                v[4] = bf2f(u.z & 0xffffu); v[5] = bf2f(u.z >> 16);
                v[6] = bf2f(u.w & 0xffffu); v[7] = bf2f(u.w >> 16);
            }
        } else {
            #pragma unroll
            for (int j = 0; j < 8; ++j) v[j] = 0.f;
        }
        if (scale) {
            #pragma unroll
            for (int j = 0; j < 8; ++j)
                v[j] = fmaxf(v[j] * scale[k0 + akc + j] + shift[k0 + akc + j], 0.f);
        }
        {
            uint4 w;
            w.x = (uint)f2bf(v[0]) | ((uint)f2bf(v[1]) << 16);
            w.y = (uint)f2bf(v[2]) | ((uint)f2bf(v[3]) << 16);
            w.z = (uint)f2bf(v[4]) | ((uint)f2bf(v[5]) << 16);
            w.w = (uint)f2bf(v[6]) | ((uint)f2bf(v[7]) << 16);
            *(uint4*)&As[ar][akc] = w;
        }
        // ---- stage W transposed ----
        {
            const float* wp = Wg + (size_t)(k0 + wk) * OUT + col0 + wcg;
            float4 y0 = *(const float4*)wp;
            float4 y1 = *(const float4*)(wp + 4);
            float wv8[8] = {y0.x, y0.y, y0.z, y0.w, y1.x, y1.y, y1.z, y1.w};
            #pragma unroll
            for (int j = 0; j < 8; ++j) Wt[wcg + j][wk] = f2bf(wv8[j]);
        }
        __syncthreads();
        // ---- MFMA ----
        short8 a = *(const short8*)&As[16 * wv + fr][kb << 3];
        #pragma unroll
        for (int ct = 0; ct < 4; ++ct) {
            short8 b = *(const short8*)&Wt[ct * 16 + fr][kb << 3];
            acc[ct] = __builtin_amdgcn_mfma_f32_16x16x32_bf16(a, b, acc[ct], 0, 0, 0);
        }
        __syncthreads();
    }

    // ---- epilogue: D row = (lane>>4)*4 + r, col = ct*16 + (lane&15) ----
    #pragma unroll
    for (int r = 0; r < 4; ++r) {
        int gr = row0 + 16 * wv + (kb << 2) + r;
        if (gr >= n) continue;
        float dv = dinv ? dinv[gr] : 1.0f;
        #pragma unroll
        for (int ct = 0; ct < 4; ++ct) {
            float val = acc[ct][r] * dv;
            int gc = col0 + ct * 16 + fr;
            if (Cb) Cb[(size_t)gr * OUT + gc] = f2bf(val);
            else    Cf[(size_t)gr * OUT + gc] = val;
        }
    }
}

// ---------------- aggregation (bf16, width 64): 8 nodes/wave, 16B/lane ----------------
// plain (scale==null):  out[i] = dinv[i] * (Hs[i] + sum_{src} Hs[src])
// fused (scale!=null):  T(v,j) = relu(v*scale[c]+shift[c]) * dinv[j]
//                       out[i] = dinv[i] * (T(Hs[i],i) + sum_{src} T(Hs[src],src))

__global__ void k_agg64_bf(const ushort* __restrict__ Hs, const float* __restrict__ dinv,
                           const int* __restrict__ rowptr, const int* __restrict__ col,
                           ushort* __restrict__ outp, int n,
                           const float* __restrict__ scale, const float* __restrict__ shift) {
    int gt = blockIdx.x * blockDim.x + threadIdx.x;
    int wave = gt >> 6;
    int lane = gt & 63;
    int sub = lane >> 3;
    int cg = (lane & 7) << 3;            // 8 channels per lane
    int node = wave * 8 + sub;
    if (node >= n) return;
    int b = rowptr[node];
    int deg = rowptr[node + 1] - b;

    float sc[8], sh[8];
    if (scale) {
        #pragma unroll
        for (int j = 0; j < 8; ++j) { sc[j] = scale[cg + j]; sh[j] = shift[cg + j]; }
    }
    float s[8];
    {
        uint4 u = *(const uint4*)(Hs + (size_t)node * 64 + cg);
        float v[8] = {bf2f(u.x & 0xffffu), bf2f(u.x >> 16), bf2f(u.y & 0xffffu), bf2f(u.y >> 16),
                      bf2f(u.z & 0xffffu), bf2f(u.z >> 16), bf2f(u.w & 0xffffu), bf2f(u.w >> 16)};
        if (scale) {
            float dv = dinv[node];
            #pragma unroll
            for (int j = 0; j < 8; ++j) s[j] = fmaxf(v[j] * sc[j] + sh[j], 0.f) * dv;
        } else {
            #pragma unroll
            for (int j = 0; j < 8; ++j) s[j] = v[j];
        }
    }
    for (int j = 0; j < deg; ++j) {
        int idx = col[b + j];
        uint4 u = *(const uint4*)(Hs + (size_t)idx * 64 + cg);
        float v[8] = {bf2f(u.x & 0xffffu), bf2f(u.x >> 16), bf2f(u.y & 0xffffu), bf2f(u.y >> 16),
                      bf2f(u.z & 0xffffu), bf2f(u.z >> 16), bf2f(u.w & 0xffffu), bf2f(u.w >> 16)};
        if (scale) {
            float dv = dinv[idx];
            #pragma unroll
            for (int q = 0; q < 8; ++q) s[q] += fmaxf(v[q] * sc[q] + sh[q], 0.f) * dv;
        } else {
            #pragma unroll
            for (int q = 0; q < 8; ++q) s[q] += v[q];
        }
    }
    float dn = dinv[node];
    uint4 o;
    o.x = (uint)f2bf(s[0] * dn) | ((uint)f2bf(s[1] * dn) << 16);
    o.y = (uint)f2bf(s[2] * dn) | ((uint)f2bf(s[3] * dn) << 16);
    o.z = (uint)f2bf(s[4] * dn) | ((uint)f2bf(s[5] * dn) << 16);
    o.w = (uint)f2bf(s[6] * dn) | ((uint)f2bf(s[7] * dn) << 16);
    *(uint4*)(outp + (size_t)node * 64 + cg) = o;
}

// ---------------- BN statistics ----------------

// bf16 input, W=64 fixed. part[b*64+c] = sum, part[(nblk+b)*64+c] = sumsq.
__global__ __launch_bounds__(256) void k_bnstat1_bf(const ushort* __restrict__ X,
                                                    float* __restrict__ part, int n) {
    int cg = threadIdx.x & 7;       // channel octet
    int rsub = threadIdx.x >> 3;    // 0..31
    int nrg = (n + 31) >> 5;
    float s[8] = {0.f}, s2[8] = {0.f};
    for (int rg = blockIdx.x; rg < nrg; rg += gridDim.x) {
        int r = (rg << 5) + rsub;
        if (r < n) {
            uint4 u = *(const uint4*)(X + (size_t)r * 64 + (cg << 3));
            float v[8] = {bf2f(u.x & 0xffffu), bf2f(u.x >> 16), bf2f(u.y & 0xffffu), bf2f(u.y >> 16),
                          bf2f(u.z & 0xffffu), bf2f(u.z >> 16), bf2f(u.w & 0xffffu), bf2f(u.w >> 16)};
            #pragma unroll
            for (int j = 0; j < 8; ++j) { s[j] += v[j]; s2[j] += v[j] * v[j]; }
        }
    }
    __shared__ float ls[256][8];
    __shared__ float ls2[256][8];
    #pragma unroll
    for (int j = 0; j < 8; ++j) { ls[threadIdx.x][j] = s[j]; ls2[threadIdx.x][j] = s2[j]; }
    __syncthreads();
    for (int off = 16; off > 0; off >>= 1) {
        if (rsub < off) {
            int i = threadIdx.x, jdx = threadIdx.x + (off << 3);
            #pragma unroll
            for (int j = 0; j < 8; ++j) { ls[i][j] += ls[jdx][j]; ls2[i][j] += ls2[jdx][j]; }
        }
        __syncthreads();
    }
    if (rsub == 0) {
        #pragma unroll
        for (int j = 0; j < 8; ++j) {
            part[(size_t)blockIdx.x * 64 + (cg << 3) + j] = ls[cg][j];
            part[(size_t)(gridDim.x + blockIdx.x) * 64 + (cg << 3) + j] = ls2[cg][j];
        }
    }
}

// f32 input (used for W=256 on d_out)
__global__ __launch_bounds__(256) void k_bnstat1(const float* __restrict__ X,
                                                 float* __restrict__ part, int n, int W) {
    int cols4 = W >> 2;
    int c4 = threadIdx.x & (cols4 - 1);
    int rsub = threadIdx.x / cols4;
    int lanes = 256 / cols4;
    int nrg = (n + lanes - 1) / lanes;
    float4 s = make_float4(0.f, 0.f, 0.f, 0.f);
    float4 s2 = make_float4(0.f, 0.f, 0.f, 0.f);
    for (int rg = blockIdx.x; rg < nrg; rg += gridDim.x) {
        int r = rg * lanes + rsub;
        if (r < n) {
            float4 v = *(const float4*)(X + (size_t)r * W + (c4 << 2));
            s.x += v.x; s.y += v.y; s.z += v.z; s.w += v.w;
            s2.x += v.x * v.x; s2.y += v.y * v.y; s2.z += v.z * v.z; s2.w += v.w * v.w;
        }
    }
    __shared__ float4 ls[256], ls2[256];
    ls[threadIdx.x] = s;
    ls2[threadIdx.x] = s2;
    __syncthreads();
    for (int off = lanes >> 1; off > 0; off >>= 1) {
        if (rsub < off) {
            int i = threadIdx.x, j = threadIdx.x + off * cols4;
            float4 a = ls[i], b = ls[j];
            a.x += b.x; a.y += b.y; a.z += b.z; a.w += b.w;
            ls[i] = a;
            float4 a2 = ls2[i], b2 = ls2[j];
            a2.x += b2.x; a2.y += b2.y; a2.z += b2.z; a2.w += b2.w;
            ls2[i] = a2;
        }
        __syncthreads();
    }
    if (rsub == 0) {
        *(float4*)(part + (size_t)blockIdx.x * W + (c4 << 2)) = ls[c4];
        *(float4*)(part + (size_t)(gridDim.x + blockIdx.x) * W + (c4 << 2)) = ls2[c4];
    }
}

__global__ __launch_bounds__(1024) void k_bnstat2(const float* __restrict__ part,
                                                  const float* __restrict__ g,
                                                  const float* __restrict__ be,
                                                  float* __restrict__ scale,
                                                  float* __restrict__ shift,
                                                  int nblk, int W, float inv_n) {
    int t = threadIdx.x;
    int c = t & (W - 1);
    int q = t / W;
    int nq = 1024 / W;
    int per = nblk / nq;
    float s = 0.f, s2 = 0.f;
    for (int b = q * per; b < (q + 1) * per; ++b) {
        s  += part[(size_t)b * W + c];
        s2 += part[(size_t)(nblk + b) * W + c];
    }
    __shared__ float ls[1024], ls2[1024];
    ls[t] = s;
    ls2[t] = s2;
    __syncthreads();
    if (q == 0) {
        for (int k = 1; k < nq; ++k) {
            s += ls[k * W + c];
            s2 += ls2[k * W + c];
        }
        float m = s * inv_n;
        float v = s2 * inv_n - m * m;
        float sc = g[c] * rsqrtf(v + BN_EPS);
        scale[c] = sc;
        shift[c] = be[c] - m * sc;
    }
}

// ---------------- final: out = relu(out*scale[c] + shift[c] + x) (in place, W=256) ----------------

__global__ void k_final(float* __restrict__ out, const float* __restrict__ x,
                        const float* __restrict__ scale, const float* __restrict__ shift, int n) {
    int idx = blockIdx.x * blockDim.x + threadIdx.x;
    int total = n * 64;
    for (int i = idx; i < total; i += gridDim.x * blockDim.x) {
        float4 v = *(const float4*)(out + (size_t)i * 4);
        float4 xv = *(const float4*)(x + (size_t)i * 4);
        int c4 = (i & 63) << 2;
        float4 sc = *(const float4*)(scale + c4);
        float4 sh = *(const float4*)(shift + c4);
        v.x = fmaxf(v.x * sc.x + sh.x + xv.x, 0.f);
        v.y = fmaxf(v.y * sc.y + sh.y + xv.y, 0.f);
        v.z = fmaxf(v.z * sc.z + sh.z + xv.z, 0.f);
        v.w = fmaxf(v.w * sc.w + sh.w + xv.w, 0.f);
        *(float4*)(out + (size_t)i * 4) = v;
    }
}

// ---------------- launch ----------------

extern "C" void kernel_launch(void* const* d_in, const int* in_sizes, int n_in,
                              void* d_out, int out_size, void* d_ws, size_t ws_size,
                              hipStream_t stream) {
    const float* x   = (const float*)d_in[0];
    const int*   ei  = (const int*)d_in[1];
    const int    N   = in_sizes[2];
    const int    E   = in_sizes[1] / 2;
    const float* W1  = (const float*)d_in[3];
    const float* g1  = (const float*)d_in[5];
    const float* be1 = (const float*)d_in[6];
    const float* W2  = (const float*)d_in[7];
    const float* g2  = (const float*)d_in[9];
    const float* be2 = (const float*)d_in[10];
    const float* W3  = (const float*)d_in[11];
    const float* g3  = (const float*)d_in[13];
    const float* be3 = (const float*)d_in[14];
    float* out = (float*)d_out;

    char* p = (char*)d_ws;
    auto alloc = [&](size_t bytes) {
        char* q = p;
        p += (bytes + 255) & ~(size_t)255;
        return q;
    };
    int*    cnt    = (int*)alloc((size_t)N * 4);
    int*    rowptr = (int*)alloc((size_t)(N + 1) * 4);
    int*    pos    = (int*)alloc((size_t)N * 4);
    int*    colv   = (int*)alloc((size_t)E * 4);
    float*  dinv   = (float*)alloc((size_t)N * 4);
    int*    bsum   = (int*)alloc(256 * 4);
    int*    boff   = (int*)alloc(256 * 4);
    ushort* bufAb  = (ushort*)alloc((size_t)N * 64 * 2);
    ushort* bufBb  = (ushort*)alloc((size_t)N * 64 * 2);
    float*  part   = (float*)alloc((size_t)2 * NBLK_STAT * 256 * 4);
    float*  scale  = (float*)alloc(256 * 4);
    float*  shift  = (float*)alloc(256 * 4);

    const int* srcp = ei;
    const int* dstp = ei + E;

    hipMemsetAsync(cnt, 0, (size_t)N * 4, stream);
    int eb = (E + 255) / 256;
    int nscan = (N + 255) / 256;
    k_degree<<<eb, 256, 0, stream>>>(dstp, cnt, E);
    k_scan1<<<nscan, 256, 0, stream>>>(cnt, bsum, N);
    k_scan2<<<1, 256, 0, stream>>>(bsum, boff, nscan);
    k_scan3<<<nscan, 256, 0, stream>>>(cnt, boff, rowptr, pos, dinv, N, E);
    k_fill<<<eb, 256, 0, stream>>>(srcp, dstp, pos, colv, E);

    dim3 gemm_g((N + 63) / 64, 1);
    dim3 gemm3_g((N + 63) / 64, 4);
    int aggb = (((N + 7) / 8) * 64 + 255) / 256;   // 8 nodes per wave

    // conv1: A1 = (x @ W1) * dinv  (bf16)  -> agg -> G1 (bf16, pre-BN)
    k_gemm_mfma<<<gemm_g, 256, 0, stream>>>(x, nullptr, W1, bufAb, nullptr,
                                            nullptr, nullptr, dinv, N, 256, 64);
    k_agg64_bf<<<aggb, 256, 0, stream>>>(bufAb, dinv, rowptr, colv, bufBb, N, nullptr, nullptr);
    k_bnstat1_bf<<<NBLK_STAT, 256, 0, stream>>>(bufBb, part, N);
    k_bnstat2<<<1, 1024, 0, stream>>>(part, g1, be1, scale, shift, NBLK_STAT, 64, 1.0f / N);

    // conv2: BN1+ReLU fused into GEMM A-stage; ×dinv epilogue -> agg -> G2 (pre-BN)
    k_gemm_mfma<<<gemm_g, 256, 0, stream>>>(nullptr, bufBb, W2, bufAb, nullptr,
                                            scale, shift, dinv, N, 64, 64);
    k_agg64_bf<<<aggb, 256, 0, stream>>>(bufAb, dinv, rowptr, colv, bufBb, N, nullptr, nullptr);
    k_bnstat1_bf<<<NBLK_STAT, 256, 0, stream>>>(bufBb, part, N);
    k_bnstat2<<<1, 1024, 0, stream>>>(part, g2, be2, scale, shift, NBLK_STAT, 64, 1.0f / N);

    // conv3 (agg-first): T-agg with BN2+ReLU+dinv fused at gather -> GEMM3 -> d_out (f32)
    k_agg64_bf<<<aggb, 256, 0, stream>>>(bufBb, dinv, rowptr, colv, bufAb, N, scale, shift);
    k_gemm_mfma<<<gemm3_g, 256, 0, stream>>>(nullptr, bufAb, W3, nullptr, out,
                                             nullptr, nullptr, nullptr, N, 64, 256);
    k_bnstat1<<<NBLK_STAT, 256, 0, stream>>>(out, part, N, 256);
    k_bnstat2<<<1, 1024, 0, stream>>>(part, g3, be3, scale, shift, NBLK_STAT, 256, 1.0f / N);

    k_final<<<2048, 256, 0, stream>>>(out, x, scale, shift, N);
}

// Round 7
// 290.120 us; speedup vs baseline: 3.0056x; 1.0829x over previous
//
#include <hip/hip_runtime.h>
#include <hip/hip_bf16.h>

#define BN_EPS 1e-5f
#define NBLK_STAT 256
#define CB_SHIFT 9            // 512 nodes per coarse bucket
#define CB_NODES 512
#define P1_CHUNK 8192

typedef __attribute__((ext_vector_type(8))) short short8;
typedef __attribute__((ext_vector_type(4))) float f32x4;

__device__ __forceinline__ ushort f2bf(float x) {
    uint u = __float_as_uint(x);
    u += 0x7FFF + ((u >> 16) & 1);      // round-to-nearest-even
    return (ushort)(u >> 16);
}
__device__ __forceinline__ float bf2f(uint h) { return __uint_as_float(h << 16); }

// ---------------- degree / CSR build ----------------

__global__ void k_degree(const int* __restrict__ dst, int* __restrict__ cnt, int E) {
    int e = blockIdx.x * blockDim.x + threadIdx.x;
    if (e < E) atomicAdd(&cnt[dst[e]], 1);
}

__global__ __launch_bounds__(256) void k_scan1(const int* __restrict__ cnt,
                                               int* __restrict__ bsum, int n) {
    __shared__ int l[256];
    int i = blockIdx.x * 256 + threadIdx.x;
    l[threadIdx.x] = (i < n) ? cnt[i] : 0;
    __syncthreads();
    for (int off = 128; off > 0; off >>= 1) {
        if (threadIdx.x < off) l[threadIdx.x] += l[threadIdx.x + off];
        __syncthreads();
    }
    if (threadIdx.x == 0) bsum[blockIdx.x] = l[0];
}

__global__ __launch_bounds__(256) void k_scan2(const int* __restrict__ bsum,
                                               int* __restrict__ boff, int nblk) {
    __shared__ int l[256];
    int t = threadIdx.x;
    l[t] = (t < nblk) ? bsum[t] : 0;
    __syncthreads();
    for (int off = 1; off < 256; off <<= 1) {
        int v = l[t];
        int add = (t >= off) ? l[t - off] : 0;
        __syncthreads();
        l[t] = v + add;
        __syncthreads();
    }
    boff[t] = (t == 0) ? 0 : l[t - 1];  // exclusive
}

// also initializes bucket bases + claim counters (bucket = 512-node range)
__global__ __launch_bounds__(256) void k_scan3(const int* __restrict__ cnt,
                                               const int* __restrict__ boff,
                                               int* __restrict__ rowptr,
                                               float* __restrict__ dinv,
                                               int* __restrict__ bucketbase,
                                               int* __restrict__ claim,
                                               int n, int E) {
    __shared__ int l[256];
    int t = threadIdx.x;
    int i = blockIdx.x * 256 + t;
    int c = (i < n) ? cnt[i] : 0;
    l[t] = c;
    __syncthreads();
    for (int off = 1; off < 256; off <<= 1) {
        int v = l[t];
        int add = (t >= off) ? l[t - off] : 0;
        __syncthreads();
        l[t] = v + add;
        __syncthreads();
    }
    if (i < n) {
        int excl = boff[blockIdx.x] + l[t] - c;
        rowptr[i] = excl;
        dinv[i] = rsqrtf((float)c + 1.0f);
        if ((i & (CB_NODES - 1)) == 0) {
            bucketbase[i >> CB_SHIFT] = excl;
            claim[i >> CB_SHIFT] = excl;
        }
    }
    if (blockIdx.x == 0 && t == 0) {
        rowptr[n] = E;
        bucketbase[(n + CB_NODES - 1) >> CB_SHIFT] = E;
    }
}

// pass 1: scatter edges into coarse-bucket-grouped key array.
// key = (dst_local << 17) | src   (requires N <= 131072)
__global__ __launch_bounds__(256) void k_p1(const int* __restrict__ src,
                                            const int* __restrict__ dst,
                                            int* __restrict__ claim,
                                            uint* __restrict__ keys,
                                            int E, int ncb) {
    __shared__ int hist[256];
    __shared__ int wpos[256];
    int tid = threadIdx.x;
    int c0 = blockIdx.x * P1_CHUNK;
    for (int b = tid; b < ncb; b += 256) hist[b] = 0;
    __syncthreads();
    for (int i = tid; i < P1_CHUNK; i += 256) {
        int e = c0 + i;
        if (e < E) atomicAdd(&hist[dst[e] >> CB_SHIFT], 1);
    }
    __syncthreads();
    for (int b = tid; b < ncb; b += 256)
        wpos[b] = hist[b] ? atomicAdd(&claim[b], hist[b]) : 0;
    __syncthreads();
    for (int i = tid; i < P1_CHUNK; i += 256) {
        int e = c0 + i;
        if (e < E) {
            int d = dst[e];
            int b = d >> CB_SHIFT;
            uint key = ((uint)(d & (CB_NODES - 1)) << 17) | (uint)src[e];
            int slot = atomicAdd(&wpos[b], 1);
            keys[slot] = key;
        }
    }
}

// pass 2: per coarse bucket, key array -> CSR col (writes confined to one ~32KB region)
__global__ __launch_bounds__(256) void k_p2(const uint* __restrict__ keys,
                                            const int* __restrict__ bucketbase,
                                            const int* __restrict__ rowptr,
                                            int* __restrict__ col, int n) {
    __shared__ int lpos[CB_NODES];
    int tid = threadIdx.x;
    int cb = blockIdx.x;
    int lo = bucketbase[cb], hi = bucketbase[cb + 1];
    for (int i = tid; i < CB_NODES; i += 256) lpos[i] = 0;
    __syncthreads();
    for (int j = lo + tid; j < hi; j += 256) {
        uint key = keys[j];
        int nl = key >> 17;
        int node = (cb << CB_SHIFT) + nl;
        int p = rowptr[node] + atomicAdd(&lpos[nl], 1);
        col[p] = (int)(key & 0x1FFFFu);
    }
}

// ---------------- MFMA bf16 GEMM: C[n,OUT] = transform(A[n,K]) @ W[K,OUT] ----------------

__global__ __launch_bounds__(256) void k_gemm_mfma(
    const float* __restrict__ Af, const ushort* __restrict__ Ab,
    const float* __restrict__ Wg,
    ushort* __restrict__ Cb, float* __restrict__ Cf,
    const float* __restrict__ scale, const float* __restrict__ shift,
    const float* __restrict__ dinv,
    int n, int K, int OUT)
{
    __shared__ ushort As[64][40];   // [row][k]
    __shared__ ushort Wt[64][40];   // [col][k]
    const int row0 = blockIdx.x * 64;
    const int col0 = blockIdx.y * 64;
    const int tid = threadIdx.x;
    const int wv = tid >> 6;
    const int lane = tid & 63;
    const int fr = lane & 15;
    const int kb = lane >> 4;

    const int ar  = tid >> 2;
    const int akc = (tid & 3) << 3;
    const int wk  = tid >> 3;
    const int wcg = (tid & 7) << 3;

    f32x4 acc[4];
    acc[0] = acc[1] = acc[2] = acc[3] = (f32x4){0.f, 0.f, 0.f, 0.f};

    for (int k0 = 0; k0 < K; k0 += 32) {
        float v[8];
        int gr = row0 + ar;
        if (gr < n) {
            if (Af) {
                const float* ap = Af + (size_t)gr * K + k0 + akc;
                float4 x0 = *(const float4*)ap;
                float4 x1 = *(const float4*)(ap + 4);
                v[0] = x0.x; v[1] = x0.y; v[2] = x0.z; v[3] = x0.w;
                v[4] = x1.x; v[5] = x1.y; v[6] = x1.z; v[7] = x1.w;
            } else {
                uint4 u = *(const uint4*)(Ab + (size_t)gr * K + k0 + akc);
                v[0] = bf2f(u.x & 0xffffu); v[1] = bf2f(u.x >> 16);
                v[2] = bf2f(u.y & 0xffffu); v[3] = bf2f(u.y >> 16);
                v[4] = bf2f(u.z & 0xffffu); v[5] = bf2f(u.z >> 16);
                v[6] = bf2f(u.w & 0xffffu); v[7] = bf2f(u.w >> 16);
            }
        } else {
            #pragma unroll
            for (int j = 0; j < 8; ++j) v[j] = 0.f;
        }
        if (scale) {
            #pragma unroll
            for (int j = 0; j < 8; ++j)
                v[j] = fmaxf(v[j] * scale[k0 + akc + j] + shift[k0 + akc + j], 0.f);
        }
        {
            uint4 w;
            w.x = (uint)f2bf(v[0]) | ((uint)f2bf(v[1]) << 16);
            w.y = (uint)f2bf(v[2]) | ((uint)f2bf(v[3]) << 16);
            w.z = (uint)f2bf(v[4]) | ((uint)f2bf(v[5]) << 16);
            w.w = (uint)f2bf(v[6]) | ((uint)f2bf(v[7]) << 16);
            *(uint4*)&As[ar][akc] = w;
        }
        {
            const float* wp = Wg + (size_t)(k0 + wk) * OUT + col0 + wcg;
            float4 y0 = *(const float4*)wp;
            float4 y1 = *(const float4*)(wp + 4);
            float wv8[8] = {y0.x, y0.y, y0.z, y0.w, y1.x, y1.y, y1.z, y1.w};
            #pragma unroll
            for (int j = 0; j < 8; ++j) Wt[wcg + j][wk] = f2bf(wv8[j]);
        }
        __syncthreads();
        short8 a = *(const short8*)&As[16 * wv + fr][kb << 3];
        #pragma unroll
        for (int ct = 0; ct < 4; ++ct) {
            short8 b = *(const short8*)&Wt[ct * 16 + fr][kb << 3];
            acc[ct] = __builtin_amdgcn_mfma_f32_16x16x32_bf16(a, b, acc[ct], 0, 0, 0);
        }
        __syncthreads();
    }

    #pragma unroll
    for (int r = 0; r < 4; ++r) {
        int gr = row0 + 16 * wv + (kb << 2) + r;
        if (gr >= n) continue;
        float dv = dinv ? dinv[gr] : 1.0f;
        #pragma unroll
        for (int ct = 0; ct < 4; ++ct) {
            float val = acc[ct][r] * dv;
            int gc = col0 + ct * 16 + fr;
            if (Cb) Cb[(size_t)gr * OUT + gc] = f2bf(val);
            else    Cf[(size_t)gr * OUT + gc] = val;
        }
    }
}

// ---------------- aggregation (bf16, width 64): 8 nodes/wave, 16B/lane ----------------

__global__ void k_agg64_bf(const ushort* __restrict__ Hs, const float* __restrict__ dinv,
                           const int* __restrict__ rowptr, const int* __restrict__ col,
                           ushort* __restrict__ outp, int n,
                           const float* __restrict__ scale, const float* __restrict__ shift) {
    int gt = blockIdx.x * blockDim.x + threadIdx.x;
    int wave = gt >> 6;
    int lane = gt & 63;
    int sub = lane >> 3;
    int cg = (lane & 7) << 3;
    int node = wave * 8 + sub;
    if (node >= n) return;
    int b = rowptr[node];
    int deg = rowptr[node + 1] - b;

    float sc[8], sh[8];
    if (scale) {
        #pragma unroll
        for (int j = 0; j < 8; ++j) { sc[j] = scale[cg + j]; sh[j] = shift[cg + j]; }
    }
    float s[8];
    {
        uint4 u = *(const uint4*)(Hs + (size_t)node * 64 + cg);
        float v[8] = {bf2f(u.x & 0xffffu), bf2f(u.x >> 16), bf2f(u.y & 0xffffu), bf2f(u.y >> 16),
                      bf2f(u.z & 0xffffu), bf2f(u.z >> 16), bf2f(u.w & 0xffffu), bf2f(u.w >> 16)};
        if (scale) {
            float dv = dinv[node];
            #pragma unroll
            for (int j = 0; j < 8; ++j) s[j] = fmaxf(v[j] * sc[j] + sh[j], 0.f) * dv;
        } else {
            #pragma unroll
            for (int j = 0; j < 8; ++j) s[j] = v[j];
        }
    }
    for (int j = 0; j < deg; ++j) {
        int idx = col[b + j];
        uint4 u = *(const uint4*)(Hs + (size_t)idx * 64 + cg);
        float v[8] = {bf2f(u.x & 0xffffu), bf2f(u.x >> 16), bf2f(u.y & 0xffffu), bf2f(u.y >> 16),
                      bf2f(u.z & 0xffffu), bf2f(u.z >> 16), bf2f(u.w & 0xffffu), bf2f(u.w >> 16)};
        if (scale) {
            float dv = dinv[idx];
            #pragma unroll
            for (int q = 0; q < 8; ++q) s[q] += fmaxf(v[q] * sc[q] + sh[q], 0.f) * dv;
        } else {
            #pragma unroll
            for (int q = 0; q < 8; ++q) s[q] += v[q];
        }
    }
    float dn = dinv[node];
    uint4 o;
    o.x = (uint)f2bf(s[0] * dn) | ((uint)f2bf(s[1] * dn) << 16);
    o.y = (uint)f2bf(s[2] * dn) | ((uint)f2bf(s[3] * dn) << 16);
    o.z = (uint)f2bf(s[4] * dn) | ((uint)f2bf(s[5] * dn) << 16);
    o.w = (uint)f2bf(s[6] * dn) | ((uint)f2bf(s[7] * dn) << 16);
    *(uint4*)(outp + (size_t)node * 64 + cg) = o;
}

// ---------------- BN statistics (bf16 input, W = 64 or 256) ----------------

__global__ __launch_bounds__(256) void k_bnstat1_bf(const ushort* __restrict__ X,
                                                    float* __restrict__ part, int n, int W) {
    int cols8 = W >> 3;                 // 8 or 32
    int c8 = threadIdx.x & (cols8 - 1);
    int rsub = threadIdx.x / cols8;
    int lanes = 256 / cols8;            // 32 or 8
    int nrg = (n + lanes - 1) / lanes;
    float s[8] = {0.f}, s2[8] = {0.f};
    for (int rg = blockIdx.x; rg < nrg; rg += gridDim.x) {
        int r = rg * lanes + rsub;
        if (r < n) {
            uint4 u = *(const uint4*)(X + (size_t)r * W + (c8 << 3));
            float v[8] = {bf2f(u.x & 0xffffu), bf2f(u.x >> 16), bf2f(u.y & 0xffffu), bf2f(u.y >> 16),
                          bf2f(u.z & 0xffffu), bf2f(u.z >> 16), bf2f(u.w & 0xffffu), bf2f(u.w >> 16)};
            #pragma unroll
            for (int j = 0; j < 8; ++j) { s[j] += v[j]; s2[j] += v[j] * v[j]; }
        }
    }
    __shared__ float ls[256][8];
    __shared__ float ls2[256][8];
    #pragma unroll
    for (int j = 0; j < 8; ++j) { ls[threadIdx.x][j] = s[j]; ls2[threadIdx.x][j] = s2[j]; }
    __syncthreads();
    for (int off = lanes >> 1; off > 0; off >>= 1) {
        if (rsub < off) {
            int i = threadIdx.x, jdx = threadIdx.x + off * cols8;
            #pragma unroll
            for (int j = 0; j < 8; ++j) { ls[i][j] += ls[jdx][j]; ls2[i][j] += ls2[jdx][j]; }
        }
        __syncthreads();
    }
    if (rsub == 0) {
        #pragma unroll
        for (int j = 0; j < 8; ++j) {
            part[(size_t)blockIdx.x * W + (c8 << 3) + j] = ls[c8][j];
            part[(size_t)(gridDim.x + blockIdx.x) * W + (c8 << 3) + j] = ls2[c8][j];
        }
    }
}

__global__ __launch_bounds__(1024) void k_bnstat2(const float* __restrict__ part,
                                                  const float* __restrict__ g,
                                                  const float* __restrict__ be,
                                                  float* __restrict__ scale,
                                                  float* __restrict__ shift,
                                                  int nblk, int W, float inv_n) {
    int t = threadIdx.x;
    int c = t & (W - 1);
    int q = t / W;
    int nq = 1024 / W;
    int per = nblk / nq;
    float s = 0.f, s2 = 0.f;
    for (int b = q * per; b < (q + 1) * per; ++b) {
        s  += part[(size_t)b * W + c];
        s2 += part[(size_t)(nblk + b) * W + c];
    }
    __shared__ float ls[1024], ls2[1024];
    ls[t] = s;
    ls2[t] = s2;
    __syncthreads();
    if (q == 0) {
        for (int k = 1; k < nq; ++k) {
            s += ls[k * W + c];
            s2 += ls2[k * W + c];
        }
        float m = s * inv_n;
        float v = s2 * inv_n - m * m;
        float sc = g[c] * rsqrtf(v + BN_EPS);
        scale[c] = sc;
        shift[c] = be[c] - m * sc;
    }
}

// ---------------- final: out = relu(h*scale[c] + shift[c] + x), h bf16, W=256 ----------------

__global__ void k_final_bf(const ushort* __restrict__ h, const float* __restrict__ x,
                           float* __restrict__ out,
                           const float* __restrict__ scale, const float* __restrict__ shift, int n) {
    int idx = blockIdx.x * blockDim.x + threadIdx.x;
    int total = n * 32;                 // groups of 8 channels
    for (int i = idx; i < total; i += gridDim.x * blockDim.x) {
        int row = i >> 5;
        int c8 = (i & 31) << 3;
        uint4 u = *(const uint4*)(h + (size_t)row * 256 + c8);
        float v[8] = {bf2f(u.x & 0xffffu), bf2f(u.x >> 16), bf2f(u.y & 0xffffu), bf2f(u.y >> 16),
                      bf2f(u.z & 0xffffu), bf2f(u.z >> 16), bf2f(u.w & 0xffffu), bf2f(u.w >> 16)};
        const float* xp = x + (size_t)row * 256 + c8;
        float4 x0 = *(const float4*)xp;
        float4 x1 = *(const float4*)(xp + 4);
        float xv[8] = {x0.x, x0.y, x0.z, x0.w, x1.x, x1.y, x1.z, x1.w};
        float o[8];
        #pragma unroll
        for (int j = 0; j < 8; ++j)
            o[j] = fmaxf(v[j] * scale[c8 + j] + shift[c8 + j] + xv[j], 0.f);
        float* op = out + (size_t)row * 256 + c8;
        *(float4*)op = make_float4(o[0], o[1], o[2], o[3]);
        *(float4*)(op + 4) = make_float4(o[4], o[5], o[6], o[7]);
    }
}

// ---------------- launch ----------------

extern "C" void kernel_launch(void* const* d_in, const int* in_sizes, int n_in,
                              void* d_out, int out_size, void* d_ws, size_t ws_size,
                              hipStream_t stream) {
    const float* x   = (const float*)d_in[0];
    const int*   ei  = (const int*)d_in[1];
    const int    N   = in_sizes[2];
    const int    E   = in_sizes[1] / 2;
    const float* W1  = (const float*)d_in[3];
    const float* g1  = (const float*)d_in[5];
    const float* be1 = (const float*)d_in[6];
    const float* W2  = (const float*)d_in[7];
    const float* g2  = (const float*)d_in[9];
    const float* be2 = (const float*)d_in[10];
    const float* W3  = (const float*)d_in[11];
    const float* g3  = (const float*)d_in[13];
    const float* be3 = (const float*)d_in[14];
    float* out = (float*)d_out;

    char* p = (char*)d_ws;
    auto alloc = [&](size_t bytes) {
        char* q = p;
        p += (bytes + 255) & ~(size_t)255;
        return q;
    };
    const int NCB = (N + CB_NODES - 1) >> CB_SHIFT;
    int*    cnt    = (int*)alloc((size_t)N * 4);
    int*    rowptr = (int*)alloc((size_t)(N + 1) * 4);
    int*    colv   = (int*)alloc((size_t)E * 4);
    uint*   keys   = (uint*)alloc((size_t)E * 4);
    float*  dinv   = (float*)alloc((size_t)N * 4);
    int*    bsum   = (int*)alloc(256 * 4);
    int*    boff   = (int*)alloc(256 * 4);
    int*    bbase  = (int*)alloc((size_t)(NCB + 1) * 4);
    int*    claim  = (int*)alloc((size_t)NCB * 4);
    ushort* bufAb  = (ushort*)alloc((size_t)N * 64 * 2);
    ushort* bufBb  = (ushort*)alloc((size_t)N * 64 * 2);
    ushort* bufCb  = (ushort*)alloc((size_t)N * 256 * 2);
    float*  part   = (float*)alloc((size_t)2 * NBLK_STAT * 256 * 4);
    float*  scale  = (float*)alloc(256 * 4);
    float*  shift  = (float*)alloc(256 * 4);

    const int* srcp = ei;
    const int* dstp = ei + E;

    hipMemsetAsync(cnt, 0, (size_t)N * 4, stream);
    int eb = (E + 255) / 256;
    int nscan = (N + 255) / 256;
    k_degree<<<eb, 256, 0, stream>>>(dstp, cnt, E);
    k_scan1<<<nscan, 256, 0, stream>>>(cnt, bsum, N);
    k_scan2<<<1, 256, 0, stream>>>(bsum, boff, nscan);
    k_scan3<<<nscan, 256, 0, stream>>>(cnt, boff, rowptr, dinv, bbase, claim, N, E);
    int p1b = (E + P1_CHUNK - 1) / P1_CHUNK;
    k_p1<<<p1b, 256, 0, stream>>>(srcp, dstp, claim, keys, E, NCB);
    k_p2<<<NCB, 256, 0, stream>>>(keys, bbase, rowptr, colv, N);

    dim3 gemm_g((N + 63) / 64, 1);
    dim3 gemm3_g((N + 63) / 64, 4);
    int aggb = (((N + 7) / 8) * 64 + 255) / 256;   // 8 nodes per wave

    // conv1: A1 = (x @ W1) * dinv  (bf16)  -> agg -> G1 (bf16, pre-BN)
    k_gemm_mfma<<<gemm_g, 256, 0, stream>>>(x, nullptr, W1, bufAb, nullptr,
                                            nullptr, nullptr, dinv, N, 256, 64);
    k_agg64_bf<<<aggb, 256, 0, stream>>>(bufAb, dinv, rowptr, colv, bufBb, N, nullptr, nullptr);
    k_bnstat1_bf<<<NBLK_STAT, 256, 0, stream>>>(bufBb, part, N, 64);
    k_bnstat2<<<1, 1024, 0, stream>>>(part, g1, be1, scale, shift, NBLK_STAT, 64, 1.0f / N);

    // conv2: BN1+ReLU fused into GEMM A-stage; ×dinv epilogue -> agg -> G2 (pre-BN)
    k_gemm_mfma<<<gemm_g, 256, 0, stream>>>(nullptr, bufBb, W2, bufAb, nullptr,
                                            scale, shift, dinv, N, 64, 64);
    k_agg64_bf<<<aggb, 256, 0, stream>>>(bufAb, dinv, rowptr, colv, bufBb, N, nullptr, nullptr);
    k_bnstat1_bf<<<NBLK_STAT, 256, 0, stream>>>(bufBb, part, N, 64);
    k_bnstat2<<<1, 1024, 0, stream>>>(part, g2, be2, scale, shift, NBLK_STAT, 64, 1.0f / N);

    // conv3 (agg-first): T-agg with BN2+ReLU+dinv fused at gather -> GEMM3 -> bufCb (bf16)
    k_agg64_bf<<<aggb, 256, 0, stream>>>(bufBb, dinv, rowptr, colv, bufAb, N, scale, shift);
    k_gemm_mfma<<<gemm3_g, 256, 0, stream>>>(nullptr, bufAb, W3, bufCb, nullptr,
                                             nullptr, nullptr, nullptr, N, 64, 256);
    k_bnstat1_bf<<<NBLK_STAT, 256, 0, stream>>>(bufCb, part, N, 256);
    k_bnstat2<<<1, 1024, 0, stream>>>(part, g3, be3, scale, shift, NBLK_STAT, 256, 1.0f / N);

    k_final_bf<<<2048, 256, 0, stream>>>(bufCb, x, out, scale, shift, N);
}